// Round 2
// baseline (789.293 us; speedup 1.0000x reference)
//
#include <hip/hip_runtime.h>
#include <cstddef>
#include <cstdint>

#define B_    4
#define T_    1024
#define F_    128
#define D_    512
#define H_    8
#define L_    4
#define DFF_  2048
#define HD_   64
#define SCALE_ 0.125f   // 1/sqrt(64)
#define LOG2E_ 1.4426950408889634f
#define CL2E_  (SCALE_ * LOG2E_)

typedef __attribute__((ext_vector_type(8))) short bf16x8;
typedef __attribute__((ext_vector_type(4))) float f32x4;

#define AS1(p) ((const __attribute__((address_space(1))) void*)(p))
#define AS3(p) ((__attribute__((address_space(3))) void*)(p))

__device__ __forceinline__ short f2bf(float f) {
    unsigned u = __float_as_uint(f);
    u += 0x7FFFu + ((u >> 16) & 1u);      // round-to-nearest-even
    return (short)(u >> 16);
}
__device__ __forceinline__ float bf2f(short s) {
    return __uint_as_float(((unsigned)(unsigned short)s) << 16);
}

// ---------------------------------------------------------------------------
// LayerNorm, fp32 in -> bf16 out
// ---------------------------------------------------------------------------
__global__ __launch_bounds__(256) void ln_k(
    const float* __restrict__ X, const float* __restrict__ w,
    const float* __restrict__ b, short* __restrict__ Y)
{
    const int row = blockIdx.x;
    const int tid = threadIdx.x;
    const float* xr = X + (size_t)row * D_;
    const float v0 = xr[tid];
    const float v1 = xr[tid + 256];
    float s  = v0 + v1;
    float s2 = v0 * v0 + v1 * v1;
#pragma unroll
    for (int off = 1; off < 64; off <<= 1) {
        s  += __shfl_xor(s,  off);
        s2 += __shfl_xor(s2, off);
    }
    __shared__ float ss[4], ss2[4];
    if ((tid & 63) == 0) { ss[tid >> 6] = s; ss2[tid >> 6] = s2; }
    __syncthreads();
    s  = ss[0]  + ss[1]  + ss[2]  + ss[3];
    s2 = ss2[0] + ss2[1] + ss2[2] + ss2[3];
    const float mean = s * (1.f / D_);
    const float var  = s2 * (1.f / D_) - mean * mean;
    const float r    = rsqrtf(var + 1e-5f);
    short* yr = Y + (size_t)row * D_;
    yr[tid]       = f2bf((v0 - mean) * r * w[tid]       + b[tid]);
    yr[tid + 256] = f2bf((v1 - mean) * r * w[tid + 256] + b[tid + 256]);
}

// ---------------------------------------------------------------------------
// ALL weight transposes in one launch
// ---------------------------------------------------------------------------
__global__ __launch_bounds__(256) void transpose_all_k(
    const float* __restrict__ qW, const float* __restrict__ kW,
    const float* __restrict__ vW, const float* __restrict__ oW,
    const float* __restrict__ f1W, const float* __restrict__ f2W,
    const float* __restrict__ nW,
    short* __restrict__ WqkvT, short* __restrict__ WoT,
    short* __restrict__ Wf1T, short* __restrict__ Wf2T,
    short* __restrict__ nWt)
{
    const int id = blockIdx.y;
    const float* src; short* dst; int K, N;
    if (id < 12) {
        const int l = id / 3, which = id % 3;
        const float* s3 = (which == 0) ? qW : (which == 1) ? kW : vW;
        src = s3 + (size_t)l * D_ * D_;
        dst = WqkvT + ((size_t)l * 3 + which) * D_ * D_;
        K = D_; N = D_;
    } else if (id < 16) {
        const int l = id - 12;
        src = oW + (size_t)l * D_ * D_;  dst = WoT + (size_t)l * D_ * D_;
        K = D_; N = D_;
    } else if (id < 20) {
        const int l = id - 16;
        src = f1W + (size_t)l * D_ * DFF_;  dst = Wf1T + (size_t)l * DFF_ * D_;
        K = D_; N = DFF_;
    } else if (id < 24) {
        const int l = id - 20;
        src = f2W + (size_t)l * DFF_ * D_;  dst = Wf2T + (size_t)l * D_ * DFF_;
        K = DFF_; N = D_;
    } else {
        src = nW; dst = nWt; K = F_; N = D_;
    }
    const int ntiles = (K >> 5) * (N >> 5);
    if ((int)blockIdx.x >= ntiles) return;
    const int nt = N >> 5;
    const int k0 = (blockIdx.x / nt) << 5, n0 = (blockIdx.x % nt) << 5;

    __shared__ float t[32][33];
    const int c = threadIdx.x, r0 = threadIdx.y;
#pragma unroll
    for (int i = 0; i < 32; i += 8)
        t[r0 + i][c] = src[(size_t)(k0 + r0 + i) * N + n0 + c];
    __syncthreads();
#pragma unroll
    for (int i = 0; i < 32; i += 8)
        dst[(size_t)(n0 + r0 + i) * K + k0 + c] = f2bf(t[c][r0 + i]);
}

// ---------------------------------------------------------------------------
// Merged prep: [0,4096) attention-bias u8 quantization,
// [4096,4608) cast nf -> bf16, [4608,4632) fused qkv bias.
// ---------------------------------------------------------------------------
__global__ __launch_bounds__(256) void prep_k(
    const int* __restrict__ et, const int* __restrict__ sp,
    const float* __restrict__ ee, const float* __restrict__ de,
    unsigned char* __restrict__ biasT8,
    const float* __restrict__ nf, short* __restrict__ nfb,
    const float* __restrict__ qb, const float* __restrict__ kb,
    const float* __restrict__ vb, float* __restrict__ biasf)
{
    const int bid = blockIdx.x;
    const int tid = threadIdx.x;
    if (bid >= 4096) {
        if (bid < 4608) {
            const int i = (((bid - 4096) << 8) + tid) << 2;
            const float4 v = *(const float4*)(nf + i);
            *(short4*)(nfb + i) =
                make_short4(f2bf(v.x), f2bf(v.y), f2bf(v.z), f2bf(v.w));
        } else {
            const int i = ((bid - 4608) << 8) + tid;
            const int l = i / 1536, c = i % 1536;
            float v;
            if (c < 512)       v = qb[l * 512 + c];
            else if (c < 1024) v = kb[l * 512 + c - 512];
            else               v = vb[l * 512 + c - 1024];
            biasf[i] = v;
        }
        return;
    }
    __shared__ float eeS[16][8], deS[21][8];
    if (tid < 128) eeS[tid >> 3][tid & 7] = ee[tid];
    for (int t = tid; t < 168; t += 256)
        deS[t >> 3][t & 7] = de[t];
    __syncthreads();
    const int gid = bid * 256 + tid;             // over B*T*T/4
    const int j4  = (gid & 255) << 2;
    const int bi  = gid >> 8;                    // b*T + i
    const size_t base = (size_t)bi * T_ + j4;
    const int4 e = *(const int4*)(et + base);
    const int4 s = *(const int4*)(sp + base);
    const int b = bi >> 10, i = bi & 1023;
    const int ex[4] = {e.x, e.y, e.z, e.w};
    const int sx[4] = {min(s.x, 20), min(s.y, 20), min(s.z, 20), min(s.w, 20)};
#pragma unroll
    for (int h = 0; h < 8; ++h) {
        uchar4 o;
        float v;
        v = (eeS[ex[0]][h] + deS[sx[0]][h]) * LOG2E_ + 0.5f;
        o.x = (unsigned char)(int)fminf(fmaxf(v * 255.f + 0.5f, 0.f), 255.f);
        v = (eeS[ex[1]][h] + deS[sx[1]][h]) * LOG2E_ + 0.5f;
        o.y = (unsigned char)(int)fminf(fmaxf(v * 255.f + 0.5f, 0.f), 255.f);
        v = (eeS[ex[2]][h] + deS[sx[2]][h]) * LOG2E_ + 0.5f;
        o.z = (unsigned char)(int)fminf(fmaxf(v * 255.f + 0.5f, 0.f), 255.f);
        v = (eeS[ex[3]][h] + deS[sx[3]][h]) * LOG2E_ + 0.5f;
        o.w = (unsigned char)(int)fminf(fmaxf(v * 255.f + 0.5f, 0.f), 255.f);
        *(uchar4*)(biasT8 + ((size_t)((b * H_ + h) * T_ + i)) * T_ + j4) = o;
    }
}

// ---------------------------------------------------------------------------
// Embedding as MFMA GEMM, 128x64 tile, K=128 (double-buffered prefetch)
// ---------------------------------------------------------------------------
__global__ __launch_bounds__(256) void embed_mm_k(
    const short* __restrict__ A, const short* __restrict__ Wt,
    const float* __restrict__ nb, const float* __restrict__ cb,
    const float* __restrict__ cW, const float* __restrict__ cent,
    float* __restrict__ C)
{
    const int K = F_, N = D_;
    __shared__ short As[2][128 * 32];
    __shared__ short Bs[2][64 * 32];
    const int tid  = threadIdx.x;
    const int lane = tid & 63, wv = tid >> 6;
    const int bm = blockIdx.y << 7, bn = blockIdx.x << 6;
    const int wm = (wv & 1) << 6, wn = (wv >> 1) << 5;

    const int c0 = (wv << 6) + lane;
    const int m0 = c0 >> 2, q0 = (c0 & 3) ^ ((m0 >> 1) & 3);
    const int c1 = 256 + c0;
    const int m1 = c1 >> 2, q1 = (c1 & 3) ^ ((m1 >> 1) & 3);

    const short* gA0 = A  + (size_t)(bm + m0) * K + (q0 << 3);
    const short* gA1 = A  + (size_t)(bm + m1) * K + (q1 << 3);
    const short* gB0 = Wt + (size_t)(bn + m0) * K + (q0 << 3);

    f32x4 acc[4][2];
#pragma unroll
    for (int i = 0; i < 4; ++i)
#pragma unroll
        for (int j = 0; j < 2; ++j)
            acc[i][j] = (f32x4){0.f, 0.f, 0.f, 0.f};

    const int fm = lane & 15, fq = lane >> 4;
    int caddr[4], baddr[2];
#pragma unroll
    for (int t = 0; t < 4; ++t) {
        const int rowA = wm + (t << 4) + fm;
        caddr[t] = ((rowA << 2) + (fq ^ ((rowA >> 1) & 3))) << 3;
    }
#pragma unroll
    for (int t = 0; t < 2; ++t) {
        const int rowB = wn + (t << 4) + fm;
        baddr[t] = ((rowB << 2) + (fq ^ ((rowB >> 1) & 3))) << 3;
    }

#define EMB_STAGE(KK, BUF) do { \
    __builtin_amdgcn_global_load_lds(AS1(gA0 + (KK)), AS3(&As[BUF][(wv << 9)]),        16, 0, 0); \
    __builtin_amdgcn_global_load_lds(AS1(gA1 + (KK)), AS3(&As[BUF][2048 + (wv << 9)]), 16, 0, 0); \
    __builtin_amdgcn_global_load_lds(AS1(gB0 + (KK)), AS3(&Bs[BUF][(wv << 9)]),        16, 0, 0); \
} while (0)

    EMB_STAGE(0, 0);
    int cur = 0;
    for (int k0 = 0; k0 < K; k0 += 32) {
        __syncthreads();                       // drains stage for tile(cur)
        if (k0 + 32 < K) EMB_STAGE(k0 + 32, cur ^ 1);
        const short* Asc = As[cur];
        const short* Bsc = Bs[cur];
        bf16x8 af[4], bf[2];
#pragma unroll
        for (int t = 0; t < 4; ++t) af[t] = *(const bf16x8*)(Asc + caddr[t]);
#pragma unroll
        for (int t = 0; t < 2; ++t) bf[t] = *(const bf16x8*)(Bsc + baddr[t]);
#pragma unroll
        for (int i = 0; i < 4; ++i)
#pragma unroll
            for (int j = 0; j < 2; ++j)
                acc[i][j] = __builtin_amdgcn_mfma_f32_16x16x32_bf16(
                    af[i], bf[j], acc[i][j], 0, 0, 0);
        cur ^= 1;
    }
#undef EMB_STAGE

    const int col0 = bn + wn + fm;
    const int row0 = bm + wm + (fq << 2);
#pragma unroll
    for (int j = 0; j < 2; ++j) {
        const int colg = col0 + (j << 4);
        const float bb = nb[colg] + cb[colg];
        const float cw = cW[colg];
#pragma unroll
        for (int i = 0; i < 4; ++i) {
#pragma unroll
            for (int r = 0; r < 4; ++r) {
                const int rowg = row0 + (i << 4) + r;
                C[(size_t)rowg * N + colg] = acc[i][j][r] + bb + cent[rowg] * cw;
            }
        }
    }
}

// ---------------------------------------------------------------------------
// bf16 MFMA GEMM, 128x128 tile: C = act(A @ Wt^T + bias) (+R)
// OUTM: 0 fp32, 1 bf16. Double-buffered depth-1 prefetch.
// ---------------------------------------------------------------------------
template <int OUTM, int ACT, int RES>
__global__ __launch_bounds__(256) void mm_k(
    const short* __restrict__ A, const short* __restrict__ Wt,
    const float* __restrict__ bias, const float* __restrict__ R,
    void* __restrict__ Cv, int M, int N, int K)
{
    __shared__ short As[2][128 * 32];
    __shared__ short Bs[2][128 * 32];
    const int tid  = threadIdx.x;
    const int lane = tid & 63, wv = tid >> 6;
    const int bm = blockIdx.y << 7, bn = blockIdx.x << 7;
    const int wm = (wv & 1) << 6, wn = (wv >> 1) << 6;

    const int c0 = (wv << 6) + lane;
    const int m0 = c0 >> 2, q0 = (c0 & 3) ^ ((m0 >> 1) & 3);
    const int c1 = 256 + c0;
    const int m1 = c1 >> 2, q1 = (c1 & 3) ^ ((m1 >> 1) & 3);

    const short* gA0 = A  + (size_t)(bm + m0) * K + (q0 << 3);
    const short* gA1 = A  + (size_t)(bm + m1) * K + (q1 << 3);
    const short* gB0 = Wt + (size_t)(bn + m0) * K + (q0 << 3);
    const short* gB1 = Wt + (size_t)(bn + m1) * K + (q1 << 3);

    f32x4 acc[4][4];
#pragma unroll
    for (int i = 0; i < 4; ++i)
#pragma unroll
        for (int j = 0; j < 4; ++j)
            acc[i][j] = (f32x4){0.f, 0.f, 0.f, 0.f};

    const int fm = lane & 15, fq = lane >> 4;
    int caddr[4], baddr[4];
#pragma unroll
    for (int t = 0; t < 4; ++t) {
        const int rowA = wm + (t << 4) + fm;
        caddr[t] = ((rowA << 2) + (fq ^ ((rowA >> 1) & 3))) << 3;
        const int rowB = wn + (t << 4) + fm;
        baddr[t] = ((rowB << 2) + (fq ^ ((rowB >> 1) & 3))) << 3;
    }

#define MM_STAGE(KK, BUF) do { \
    __builtin_amdgcn_global_load_lds(AS1(gA0 + (KK)), AS3(&As[BUF][(wv << 9)]),        16, 0, 0); \
    __builtin_amdgcn_global_load_lds(AS1(gA1 + (KK)), AS3(&As[BUF][2048 + (wv << 9)]), 16, 0, 0); \
    __builtin_amdgcn_global_load_lds(AS1(gB0 + (KK)), AS3(&Bs[BUF][(wv << 9)]),        16, 0, 0); \
    __builtin_amdgcn_global_load_lds(AS1(gB1 + (KK)), AS3(&Bs[BUF][2048 + (wv << 9)]), 16, 0, 0); \
} while (0)

    MM_STAGE(0, 0);
    int cur = 0;
    for (int k0 = 0; k0 < K; k0 += 32) {
        __syncthreads();                       // drains stage for tile(cur)
        if (k0 + 32 < K) MM_STAGE(k0 + 32, cur ^ 1);
        const short* Asc = As[cur];
        const short* Bsc = Bs[cur];
        bf16x8 af[4], bf[4];
#pragma unroll
        for (int t = 0; t < 4; ++t) {
            af[t] = *(const bf16x8*)(Asc + caddr[t]);
            bf[t] = *(const bf16x8*)(Bsc + baddr[t]);
        }
#pragma unroll
        for (int i = 0; i < 4; ++i)
#pragma unroll
            for (int j = 0; j < 4; ++j)
                acc[i][j] = __builtin_amdgcn_mfma_f32_16x16x32_bf16(
                    af[i], bf[j], acc[i][j], 0, 0, 0);
        cur ^= 1;
    }
#undef MM_STAGE

    const int col0 = bn + wn + fm;
    const int row0 = bm + wm + (fq << 2);
    float* Cf = (float*)Cv;
    short* Cb = (short*)Cv;
#pragma unroll
    for (int j = 0; j < 4; ++j) {
        const int colg = col0 + (j << 4);
        const float bb = bias[colg];
#pragma unroll
        for (int i = 0; i < 4; ++i) {
#pragma unroll
            for (int r = 0; r < 4; ++r) {
                const int rowg = row0 + (i << 4) + r;
                float v = acc[i][j][r] + bb;
                if (ACT) v = v / (1.f + __expf(-v));
                const size_t off = (size_t)rowg * N + colg;
                if (RES) v += R[off];
                if (OUTM == 1) Cb[off] = f2bf(v);
                else           Cf[off] = v;
            }
        }
    }
}

// ---------------------------------------------------------------------------
// QKV GEMM, 128x64 tile (768 blocks). N=1536 fixed. Double-buffered.
// Q,K -> QKb [M][1024]; V -> Vt [B*H][64][T] (transposed scatter).
// ---------------------------------------------------------------------------
__global__ __launch_bounds__(256) void qkv64_k(
    const short* __restrict__ A, const short* __restrict__ Wt,
    const float* __restrict__ bias, short* __restrict__ QKb,
    short* __restrict__ VtOut)
{
    const int K = D_;
    __shared__ short As[2][128 * 32];
    __shared__ short Bs[2][64 * 32];
    const int tid  = threadIdx.x;
    const int lane = tid & 63, wv = tid >> 6;
    const int bm = blockIdx.y << 7, bn = blockIdx.x << 6;
    const int wm = (wv & 1) << 6, wn = (wv >> 1) << 5;

    const int c0 = (wv << 6) + lane;
    const int m0 = c0 >> 2, q0 = (c0 & 3) ^ ((m0 >> 1) & 3);
    const int c1 = 256 + c0;
    const int m1 = c1 >> 2, q1 = (c1 & 3) ^ ((m1 >> 1) & 3);

    const short* gA0 = A  + (size_t)(bm + m0) * K + (q0 << 3);
    const short* gA1 = A  + (size_t)(bm + m1) * K + (q1 << 3);
    const short* gB0 = Wt + (size_t)(bn + m0) * K + (q0 << 3);

    f32x4 acc[4][2];
#pragma unroll
    for (int i = 0; i < 4; ++i)
#pragma unroll
        for (int j = 0; j < 2; ++j)
            acc[i][j] = (f32x4){0.f, 0.f, 0.f, 0.f};

    const int fm = lane & 15, fq = lane >> 4;
    int caddr[4], baddr[2];
#pragma unroll
    for (int t = 0; t < 4; ++t) {
        const int rowA = wm + (t << 4) + fm;
        caddr[t] = ((rowA << 2) + (fq ^ ((rowA >> 1) & 3))) << 3;
    }
#pragma unroll
    for (int t = 0; t < 2; ++t) {
        const int rowB = wn + (t << 4) + fm;
        baddr[t] = ((rowB << 2) + (fq ^ ((rowB >> 1) & 3))) << 3;
    }

#define QKV_STAGE(KK, BUF) do { \
    __builtin_amdgcn_global_load_lds(AS1(gA0 + (KK)), AS3(&As[BUF][(wv << 9)]),        16, 0, 0); \
    __builtin_amdgcn_global_load_lds(AS1(gA1 + (KK)), AS3(&As[BUF][2048 + (wv << 9)]), 16, 0, 0); \
    __builtin_amdgcn_global_load_lds(AS1(gB0 + (KK)), AS3(&Bs[BUF][(wv << 9)]),        16, 0, 0); \
} while (0)

    QKV_STAGE(0, 0);
    int cur = 0;
    for (int k0 = 0; k0 < K; k0 += 32) {
        __syncthreads();                       // drains stage for tile(cur)
        if (k0 + 32 < K) QKV_STAGE(k0 + 32, cur ^ 1);
        const short* Asc = As[cur];
        const short* Bsc = Bs[cur];
        bf16x8 af[4], bf[2];
#pragma unroll
        for (int t = 0; t < 4; ++t) af[t] = *(const bf16x8*)(Asc + caddr[t]);
#pragma unroll
        for (int t = 0; t < 2; ++t) bf[t] = *(const bf16x8*)(Bsc + baddr[t]);
#pragma unroll
        for (int i = 0; i < 4; ++i)
#pragma unroll
            for (int j = 0; j < 2; ++j)
                acc[i][j] = __builtin_amdgcn_mfma_f32_16x16x32_bf16(
                    af[i], bf[j], acc[i][j], 0, 0, 0);
        cur ^= 1;
    }
#undef QKV_STAGE

    const int col0 = bn + wn + fm;
    const int row0 = bm + wm + (fq << 2);
#pragma unroll
    for (int j = 0; j < 2; ++j) {
        const int colg = col0 + (j << 4);
        const float bb = bias[colg];
#pragma unroll
        for (int i = 0; i < 4; ++i) {
#pragma unroll
            for (int r = 0; r < 4; ++r) {
                const int rowg = row0 + (i << 4) + r;
                const float v = acc[i][j][r] + bb;
                if (colg < 1024) {
                    QKb[(size_t)rowg * 1024 + colg] = f2bf(v);
                } else {
                    const int da = colg - 1024;
                    const int hh = da >> 6, dd = da & 63;
                    const int bb2 = rowg >> 10, tt = rowg & 1023;
                    VtOut[((size_t)(bb2 * H_ + hh) * 64 + dd) * T_ + tt] = f2bf(v);
                }
            }
        }
    }
}

// ---------------------------------------------------------------------------
// MFMA flash attention v3.2 (single-buffered — reverted from v3.3: the 2x
// LDS cost dropped residency 4->3 blocks/CU and regressed).
// grid (2*T/64, H, B), 256 threads = 4 waves.
// ---------------------------------------------------------------------------
__global__ __launch_bounds__(256) void flash_k(
    const short* __restrict__ QKb, const short* __restrict__ Vt,
    const unsigned char* __restrict__ biasT8, short* __restrict__ OpartB,
    float* __restrict__ Lpart)
{
    const int tid = threadIdx.x;
    const int bx = blockIdx.x;
    const int it = bx >> 1, split = bx & 1;
    const int i0 = it << 6;
    const int h  = blockIdx.y;
    const int b  = blockIdx.z;
    const int lane = tid & 63, w = tid >> 6;
    const int fm = lane & 15, q = lane >> 4;

    __shared__ short Ks[4096];          // 64 rows x 8 chunks(16B), chunk ^= row&7
    __shared__ short Vs[4096];
    __shared__ unsigned char Bsh8[4096]; // 64 rows x 4 chunks(16B), chunk ^= row&3
    __shared__ short Ps[64][72];

    const short* qp = QKb + (size_t)(b * T_ + i0 + (w << 4) + fm) * 1024 + (h << 6) + (q << 3);
    const bf16x8 aq0 = *(const bf16x8*)(qp);
    const bf16x8 aq1 = *(const bf16x8*)(qp + 32);

    const int s0 = (w << 6) + lane, r0 = s0 >> 3, cc0 = (s0 & 7) ^ (r0 & 7);
    const int s1 = 256 + s0,        r1 = s1 >> 3, cc1 = (s1 & 7) ^ (r1 & 7);
    const short* gK0 = QKb + (size_t)(b * T_ + r0) * 1024 + 512 + (h << 6) + (cc0 << 3);
    const short* gK1 = QKb + (size_t)(b * T_ + r1) * 1024 + 512 + (h << 6) + (cc1 << 3);
    const short* gV0 = Vt + ((size_t)((b * H_ + h) << 6) + r0) * T_ + (cc0 << 3);
    const short* gV1 = Vt + ((size_t)((b * H_ + h) << 6) + r1) * T_ + (cc1 << 3);
    // u8 bias tile: 256 chunks of 16B; slot s0 -> row s0>>2, chunk (s0&3)^(row&3)
    const int br = s0 >> 2, bc = (s0 & 3) ^ (br & 3);
    const unsigned char* gB0 = biasT8 +
        ((size_t)(b * H_ + h) * T_ + i0 + br) * T_ + (bc << 4);

    int fAddr[4][2];
#pragma unroll
    for (int t = 0; t < 4; ++t) {
        const int row = (t << 4) + fm;
#pragma unroll
        for (int ks = 0; ks < 2; ++ks)
            fAddr[t][ks] = (row << 6) + (((q + (ks << 2)) ^ (row & 7)) << 3);
    }

    // u8 bias LDS read addrs
    int bAddr[4][4];
#pragma unroll
    for (int r = 0; r < 4; ++r) {
        const int rowL = (w << 4) + (q << 2) + r;
#pragma unroll
        for (int jt = 0; jt < 4; ++jt)
            bAddr[r][jt] = (rowL << 6) + (((jt ^ (rowL & 3))) << 4) + fm;
    }

    const short oneb = 0x3F80;                   // bf16 1.0
    const bf16x8 ones = {oneb, oneb, oneb, oneb, oneb, oneb, oneb, oneb};

    f32x4 accO[4];
#pragma unroll
    for (int dt = 0; dt < 4; ++dt) accO[dt] = (f32x4){0.f, 0.f, 0.f, 0.f};
    f32x4 accL = (f32x4){0.f, 0.f, 0.f, 0.f};

    const int irow = b * T_ + i0 + (w << 4) + (q << 2);
    short* psW = &Ps[(w << 4) + (q << 2)][fm];
    const short* psR = &Ps[(w << 4) + fm][q << 3];

    const int jbeg = split << 9, jend = jbeg + 512;
    for (int j0 = jbeg; j0 < jend; j0 += 64) {
        __syncthreads();
        __builtin_amdgcn_global_load_lds(AS1(gK0 + (size_t)j0 * 1024), AS3(Ks + (s0 << 3)), 16, 0, 0);
        __builtin_amdgcn_global_load_lds(AS1(gK1 + (size_t)j0 * 1024), AS3(Ks + (s1 << 3)), 16, 0, 0);
        __builtin_amdgcn_global_load_lds(AS1(gV0 + j0), AS3(Vs + (s0 << 3)), 16, 0, 0);
        __builtin_amdgcn_global_load_lds(AS1(gV1 + j0), AS3(Vs + (s1 << 3)), 16, 0, 0);
        __builtin_amdgcn_global_load_lds(AS1(gB0 + j0), AS3(Bsh8 + (s0 << 4)), 16, 0, 0);
        __syncthreads();

        f32x4 s[4];
#pragma unroll
        for (int jt = 0; jt < 4; ++jt) s[jt] = (f32x4){0.f, 0.f, 0.f, 0.f};
#pragma unroll
        for (int jt = 0; jt < 4; ++jt) {
            const bf16x8 k0 = *(const bf16x8*)(Ks + fAddr[jt][0]);
            const bf16x8 k1 = *(const bf16x8*)(Ks + fAddr[jt][1]);
            s[jt] = __builtin_amdgcn_mfma_f32_16x16x32_bf16(aq0, k0, s[jt], 0, 0, 0);
            s[jt] = __builtin_amdgcn_mfma_f32_16x16x32_bf16(aq1, k1, s[jt], 0, 0, 0);
        }

        // P = 2^(s*scale*log2e + (q8/255 - 0.5)) — fixed max, direct to LDS
#pragma unroll
        for (int r = 0; r < 4; ++r)
#pragma unroll
            for (int jt = 0; jt < 4; ++jt) {
                const float q8 = (float)Bsh8[bAddr[r][jt]];
                const float bb = fmaf(q8, 1.f / 255.f, -0.5f);
                const float p = __builtin_amdgcn_exp2f(fmaf(s[jt][r], CL2E_, bb));
                psW[(size_t)r * 72 + (jt << 4)] = f2bf(p);
            }

        // O += P V ; l += P @ ones (MFMA row-sum)
#pragma unroll
        for (int ks = 0; ks < 2; ++ks) {
            const bf16x8 ap = *(const bf16x8*)(psR + (ks << 5));
            accL = __builtin_amdgcn_mfma_f32_16x16x32_bf16(ap, ones, accL, 0, 0, 0);
#pragma unroll
            for (int dt = 0; dt < 4; ++dt) {
                const bf16x8 bv = *(const bf16x8*)(Vs + fAddr[dt][ks]);
                accO[dt] = __builtin_amdgcn_mfma_f32_16x16x32_bf16(ap, bv, accO[dt], 0, 0, 0);
            }
        }
    }

    short* obase = OpartB + (size_t)split * B_ * T_ * D_;
#pragma unroll
    for (int r = 0; r < 4; ++r) {
        short* op = obase + (size_t)(irow + r) * D_ + (h << 6) + fm;
#pragma unroll
        for (int dt = 0; dt < 4; ++dt)
            op[dt << 4] = f2bf(accO[dt][r]);
    }
    if (fm == 0) {
#pragma unroll
        for (int r = 0; r < 4; ++r)
            Lpart[(size_t)split * B_ * T_ * H_ + (size_t)(irow + r) * H_ + h] = accL[r];
    }
}

// ---------------------------------------------------------------------------
// Combine split-K attention partials: Ob = bf16((O0+O1) / (l0+l1))
// ---------------------------------------------------------------------------
__global__ __launch_bounds__(256) void combine_k(
    const short* __restrict__ OpartB, const float* __restrict__ Lpart,
    short* __restrict__ Ob)
{
    const int gid = blockIdx.x * 256 + threadIdx.x;   // over M*D/4
    const int d4  = (gid & 127) << 2;
    const int row = gid >> 7;
    const int h   = d4 >> 6;
    const float l = Lpart[(size_t)row * H_ + h] +
                    Lpart[(size_t)B_ * T_ * H_ + (size_t)row * H_ + h];
    const float inv = 1.f / l;
    const size_t o = (size_t)row * D_ + d4;
    const short4 a = *(const short4*)(OpartB + o);
    const short4 c = *(const short4*)(OpartB + (size_t)B_ * T_ * D_ + o);
    short4 r = make_short4(
        f2bf((bf2f(a.x) + bf2f(c.x)) * inv), f2bf((bf2f(a.y) + bf2f(c.y)) * inv),
        f2bf((bf2f(a.z) + bf2f(c.z)) * inv), f2bf((bf2f(a.w) + bf2f(c.w)) * inv));
    *(short4*)(Ob + o) = r;
}

// ---------------------------------------------------------------------------
// bf16 MFMA GEMM, 128x64 tile, SPLIT-K with fp32 atomic accumulation.
// C (fp32) must already hold the residual; blockIdx.z==0 adds bias.
// Grid (N/64, M/128, SPLIT) -> 4x the blocks of the old mm64_k, which was
// 1 block/CU (Occupancy 9%, MfmaUtil 7% = pure exposed latency). TLP from
// 4 blocks/CU hides the per-K-step staging latency.
// ---------------------------------------------------------------------------
__global__ __launch_bounds__(256) void mm64sk_k(
    const short* __restrict__ A, const short* __restrict__ Wt,
    const float* __restrict__ bias, float* __restrict__ C,
    int M, int N, int K, int KS)
{
    __shared__ short As[2][128 * 32];
    __shared__ short Bs[2][64 * 32];
    const int tid  = threadIdx.x;
    const int lane = tid & 63, wv = tid >> 6;
    const int bm = blockIdx.y << 7, bn = blockIdx.x << 6;
    const int ks0 = blockIdx.z * KS;
    const int wm = (wv & 1) << 6, wn = (wv >> 1) << 5;

    const int c0 = (wv << 6) + lane;
    const int m0 = c0 >> 2, q0 = (c0 & 3) ^ ((m0 >> 1) & 3);
    const int c1 = 256 + c0;
    const int m1 = c1 >> 2, q1 = (c1 & 3) ^ ((m1 >> 1) & 3);

    const short* gA0 = A  + (size_t)(bm + m0) * K + ks0 + (q0 << 3);
    const short* gA1 = A  + (size_t)(bm + m1) * K + ks0 + (q1 << 3);
    const short* gB0 = Wt + (size_t)(bn + m0) * K + ks0 + (q0 << 3);

    f32x4 acc[4][2];
#pragma unroll
    for (int i = 0; i < 4; ++i)
#pragma unroll
        for (int j = 0; j < 2; ++j)
            acc[i][j] = (f32x4){0.f, 0.f, 0.f, 0.f};

    const int fm = lane & 15, fq = lane >> 4;
    int caddr[4], baddr[2];
#pragma unroll
    for (int t = 0; t < 4; ++t) {
        const int rowA = wm + (t << 4) + fm;
        caddr[t] = ((rowA << 2) + (fq ^ ((rowA >> 1) & 3))) << 3;
    }
#pragma unroll
    for (int t = 0; t < 2; ++t) {
        const int rowB = wn + (t << 4) + fm;
        baddr[t] = ((rowB << 2) + (fq ^ ((rowB >> 1) & 3))) << 3;
    }

#define MM64_STAGE(KK, BUF) do { \
    __builtin_amdgcn_global_load_lds(AS1(gA0 + (KK)), AS3(&As[BUF][(wv << 9)]),        16, 0, 0); \
    __builtin_amdgcn_global_load_lds(AS1(gA1 + (KK)), AS3(&As[BUF][2048 + (wv << 9)]), 16, 0, 0); \
    __builtin_amdgcn_global_load_lds(AS1(gB0 + (KK)), AS3(&Bs[BUF][(wv << 9)]),        16, 0, 0); \
} while (0)

    MM64_STAGE(0, 0);
    int cur = 0;
    for (int k0 = 0; k0 < KS; k0 += 32) {
        __syncthreads();                       // drains stage for tile(cur)
        if (k0 + 32 < KS) MM64_STAGE(k0 + 32, cur ^ 1);
        const short* Asc = As[cur];
        const short* Bsc = Bs[cur];
        bf16x8 af[4], bf[2];
#pragma unroll
        for (int t = 0; t < 4; ++t) af[t] = *(const bf16x8*)(Asc + caddr[t]);
#pragma unroll
        for (int t = 0; t < 2; ++t) bf[t] = *(const bf16x8*)(Bsc + baddr[t]);
#pragma unroll
        for (int i = 0; i < 4; ++i)
#pragma unroll
            for (int j = 0; j < 2; ++j)
                acc[i][j] = __builtin_amdgcn_mfma_f32_16x16x32_bf16(
                    af[i], bf[j], acc[i][j], 0, 0, 0);
        cur ^= 1;
    }
#undef MM64_STAGE

    const int col0 = bn + wn + fm;
    const int row0 = bm + wm + (fq << 2);
    const bool addb = (blockIdx.z == 0);
#pragma unroll
    for (int j = 0; j < 2; ++j) {
        const int colg = col0 + (j << 4);
        const float bb = addb ? bias[colg] : 0.f;
#pragma unroll
        for (int i = 0; i < 4; ++i) {
#pragma unroll
            for (int r = 0; r < 4; ++r) {
                const int rowg = row0 + (i << 4) + r;
                const size_t off = (size_t)rowg * N + colg;
                unsafeAtomicAdd(&C[off], acc[i][j][r] + bb);
            }
        }
    }
}

// ---------------------------------------------------------------------------
// Final copy Hbuf -> out (fp32, vectorized)
// ---------------------------------------------------------------------------
__global__ __launch_bounds__(256) void copy_k(
    const float* __restrict__ S, float* __restrict__ Dst)
{
    const int i = (blockIdx.x * 256 + threadIdx.x) << 2;
    *(float4*)(Dst + i) = *(const float4*)(S + i);
}

// ---------------------------------------------------------------------------
extern "C" void kernel_launch(void* const* d_in, const int* in_sizes, int n_in,
                              void* d_out, int out_size, void* d_ws, size_t ws_size,
                              hipStream_t stream)
{
    (void)in_sizes; (void)n_in; (void)out_size; (void)ws_size;

    const float* nf   = (const float*)d_in[0];
    const float* cent = (const float*)d_in[1];
    const int*   et   = (const int*)  d_in[2];
    const int*   sp   = (const int*)  d_in[3];
    const float* nW   = (const float*)d_in[4];
    const float* nb   = (const float*)d_in[5];
    const float* cW   = (const float*)d_in[6];
    const float* cb   = (const float*)d_in[7];
    const float* ee   = (const float*)d_in[8];
    const float* de   = (const float*)d_in[9];
    const float* ln1w = (const float*)d_in[10];
    const float* ln1b = (const float*)d_in[11];
    const float* qW   = (const float*)d_in[12];
    const float* qb   = (const float*)d_in[13];
    const float* kW   = (const float*)d_in[14];
    const float* kb   = (const float*)d_in[15];
    const float* vW   = (const float*)d_in[16];
    const float* vb   = (const float*)d_in[17];
    const float* oW   = (const float*)d_in[18];
    const float* ob   = (const float*)d_in[19];
    const float* ln2w = (const float*)d_in[20];
    const float* ln2b = (const float*)d_in[21];
    const float* f1W  = (const float*)d_in[22];
    const float* f1b  = (const float*)d_in[23];
    const float* f2W  = (const float*)d_in[24];
    const float* f2b  = (const float*)d_in[25];

    const int M = B_ * T_;                          // 4096
    char* p = (char*)d_ws;
    float* Hbuf  = (float*)p;  p += (size_t)M * D_ * 4;                    // 8 MB
    short* QKb   = (short*)p;  p += (size_t)M * 1024 * 2;                  // 8 MB
    short* Vt    = (short*)p;  p += (size_t)B_ * H_ * 64 * T_ * 2;         // 4 MB
    float* biasf = (float*)p;  p += (size_t)L_ * 3 * D_ * 4;               // 24 KB
    short* Xbuf  = (short*)p;  p += (size_t)M * D_ * 2;                    // 4 MB
    short* Ob    = (short*)p;  p += (size_t)M * D_ * 2;                    // 4 MB
    short* FF    = (short*)p;  p += (size_t)M * DFF_ * 2;                  // 16 MB
    unsigned char* biasT8 = (unsigned char*)p; p += (size_t)B_ * H_ * T_ * T_; // 33.5 MB
    short* WqkvT = (short*)p;  p += (size_t)L_ * 3 * D_ * D_ * 2;
    short* WoT   = (short*)p;  p += (size_t)L_ * D_ * D_ * 2;
    short* Wf1T  = (short*)p;  p += (size_t)L_ * DFF_ * D_ * 2;
    short* Wf2T  = (short*)p;  p += (size_t)L_ * D_ * DFF_ * 2;
    short* nfb   = (short*)p;  p += (size_t)M * F_ * 2;                    // 1 MB
    short* nWt   = (short*)p;  p += (size_t)D_ * F_ * 2;                   // 128 KB
    short* OpartB = (short*)p; p += (size_t)2 * M * D_ * 2;                // 8 MB
    float* Lpart = (float*)p;  p += (size_t)2 * M * H_ * 4;                // 256 KB

    float* out = (float*)d_out;

    // ---- prep (3 dispatches)
    transpose_all_k<<<dim3(1024, 25), dim3(32, 8), 0, stream>>>(
        qW, kW, vW, oW, f1W, f2W, nW, WqkvT, WoT, Wf1T, Wf2T, nWt);
    prep_k<<<dim3(4632), dim3(256), 0, stream>>>(
        et, sp, ee, de, biasT8, nf, nfb, qb, kb, vb, biasf);
    embed_mm_k<<<dim3(D_ / 64, M / 128), dim3(256), 0, stream>>>(
        nfb, nWt, nb, cb, cW, cent, Hbuf);

    const dim3 blk(256);
    const dim3 gQKV(3 * D_ / 64, M / 128);       // (24, 32) = 768 blocks
    const dim3 gO64sk(D_ / 64, M / 128, 4);      // (8, 32, 4) = 1024 blocks
    const dim3 gF1 (DFF_ / 128,  M / 128);       // (16, 32) = 512 blocks
    const dim3 gAttn(2 * T_ / 64, H_, B_);       // (32, 8, 4) = 1024 blocks
    const dim3 gCmb(M * D_ / 1024);              // 2048 blocks

    for (int l = 0; l < L_; ++l) {
        const size_t bOff  = (size_t)l * D_;
        const size_t b1Off = (size_t)l * DFF_;

        ln_k<<<dim3(M), blk, 0, stream>>>(Hbuf, ln1w + bOff, ln1b + bOff, Xbuf);

        qkv64_k<<<gQKV, blk, 0, stream>>>(
            Xbuf, WqkvT + (size_t)l * 3 * D_ * D_, biasf + (size_t)l * 3 * D_,
            QKb, Vt);

        flash_k<<<gAttn, blk, 0, stream>>>(QKb, Vt, biasT8, OpartB, Lpart);
        combine_k<<<gCmb, blk, 0, stream>>>(OpartB, Lpart, Ob);

        // O-proj: Hbuf += Ob @ WoT + ob   (split-K x4, atomic accumulate)
        mm64sk_k<<<gO64sk, blk, 0, stream>>>(
            Ob, WoT + (size_t)l * D_ * D_, ob + bOff, Hbuf, M, D_, D_, D_ / 4);

        ln_k<<<dim3(M), blk, 0, stream>>>(Hbuf, ln2w + bOff, ln2b + bOff, Xbuf);

        mm_k<1, 1, 0><<<gF1, blk, 0, stream>>>(
            Xbuf, Wf1T + (size_t)l * DFF_ * D_, f1b + b1Off, nullptr, FF, M, DFF_, D_);

        // FF2: Hbuf += FF @ Wf2T + f2b   (split-K x4, atomic accumulate)
        mm64sk_k<<<gO64sk, blk, 0, stream>>>(
            FF, Wf2T + (size_t)l * D_ * DFF_, f2b + bOff, Hbuf, M, D_, DFF_, DFF_ / 4);
    }

    copy_k<<<gCmb, blk, 0, stream>>>(Hbuf, out);
}

// Round 3
// 655.831 us; speedup vs baseline: 1.2035x; 1.2035x over previous
//
#include <hip/hip_runtime.h>
#include <cstddef>
#include <cstdint>

#define B_    4
#define T_    1024
#define F_    128
#define D_    512
#define H_    8
#define L_    4
#define DFF_  2048
#define HD_   64
#define SCALE_ 0.125f   // 1/sqrt(64)
#define LOG2E_ 1.4426950408889634f
#define CL2E_  (SCALE_ * LOG2E_)

typedef __attribute__((ext_vector_type(8))) short bf16x8;
typedef __attribute__((ext_vector_type(4))) float f32x4;

#define AS1(p) ((const __attribute__((address_space(1))) void*)(p))
#define AS3(p) ((__attribute__((address_space(3))) void*)(p))

__device__ __forceinline__ short f2bf(float f) {
    unsigned u = __float_as_uint(f);
    u += 0x7FFFu + ((u >> 16) & 1u);      // round-to-nearest-even
    return (short)(u >> 16);
}
__device__ __forceinline__ float bf2f(short s) {
    return __uint_as_float(((unsigned)(unsigned short)s) << 16);
}

// Counted-vmcnt pipeline barrier (T4): wait only for the OLDEST in-flight
// stage; keep 2 stages in flight across the barrier. L = loads per stage.
// rem = nt-1-t. "memory" clobber + sched_barrier(0) pin compiler ordering
// of ds_reads/LDS-DMA around the barrier.
#define PIPE_BARRIER(rem, W2, W1)                                             \
    if ((rem) >= 2)      asm volatile("s_waitcnt vmcnt(" #W2 ")" ::: "memory"); \
    else if ((rem) == 1) asm volatile("s_waitcnt vmcnt(" #W1 ")" ::: "memory"); \
    else                 asm volatile("s_waitcnt vmcnt(0)"      ::: "memory"); \
    __builtin_amdgcn_s_barrier();                                             \
    __builtin_amdgcn_sched_barrier(0);

// ---------------------------------------------------------------------------
// LayerNorm, fp32 in -> bf16 out
// ---------------------------------------------------------------------------
__global__ __launch_bounds__(256) void ln_k(
    const float* __restrict__ X, const float* __restrict__ w,
    const float* __restrict__ b, short* __restrict__ Y)
{
    const int row = blockIdx.x;
    const int tid = threadIdx.x;
    const float* xr = X + (size_t)row * D_;
    const float v0 = xr[tid];
    const float v1 = xr[tid + 256];
    float s  = v0 + v1;
    float s2 = v0 * v0 + v1 * v1;
#pragma unroll
    for (int off = 1; off < 64; off <<= 1) {
        s  += __shfl_xor(s,  off);
        s2 += __shfl_xor(s2, off);
    }
    __shared__ float ss[4], ss2[4];
    if ((tid & 63) == 0) { ss[tid >> 6] = s; ss2[tid >> 6] = s2; }
    __syncthreads();
    s  = ss[0]  + ss[1]  + ss[2]  + ss[3];
    s2 = ss2[0] + ss2[1] + ss2[2] + ss2[3];
    const float mean = s * (1.f / D_);
    const float var  = s2 * (1.f / D_) - mean * mean;
    const float r    = rsqrtf(var + 1e-5f);
    short* yr = Y + (size_t)row * D_;
    yr[tid]       = f2bf((v0 - mean) * r * w[tid]       + b[tid]);
    yr[tid + 256] = f2bf((v1 - mean) * r * w[tid + 256] + b[tid + 256]);
}

// ---------------------------------------------------------------------------
// ALL weight transposes in one launch
// ---------------------------------------------------------------------------
__global__ __launch_bounds__(256) void transpose_all_k(
    const float* __restrict__ qW, const float* __restrict__ kW,
    const float* __restrict__ vW, const float* __restrict__ oW,
    const float* __restrict__ f1W, const float* __restrict__ f2W,
    const float* __restrict__ nW,
    short* __restrict__ WqkvT, short* __restrict__ WoT,
    short* __restrict__ Wf1T, short* __restrict__ Wf2T,
    short* __restrict__ nWt)
{
    const int id = blockIdx.y;
    const float* src; short* dst; int K, N;
    if (id < 12) {
        const int l = id / 3, which = id % 3;
        const float* s3 = (which == 0) ? qW : (which == 1) ? kW : vW;
        src = s3 + (size_t)l * D_ * D_;
        dst = WqkvT + ((size_t)l * 3 + which) * D_ * D_;
        K = D_; N = D_;
    } else if (id < 16) {
        const int l = id - 12;
        src = oW + (size_t)l * D_ * D_;  dst = WoT + (size_t)l * D_ * D_;
        K = D_; N = D_;
    } else if (id < 20) {
        const int l = id - 16;
        src = f1W + (size_t)l * D_ * DFF_;  dst = Wf1T + (size_t)l * DFF_ * D_;
        K = D_; N = DFF_;
    } else if (id < 24) {
        const int l = id - 20;
        src = f2W + (size_t)l * DFF_ * D_;  dst = Wf2T + (size_t)l * D_ * DFF_;
        K = DFF_; N = D_;
    } else {
        src = nW; dst = nWt; K = F_; N = D_;
    }
    const int ntiles = (K >> 5) * (N >> 5);
    if ((int)blockIdx.x >= ntiles) return;
    const int nt = N >> 5;
    const int k0 = (blockIdx.x / nt) << 5, n0 = (blockIdx.x % nt) << 5;

    __shared__ float t[32][33];
    const int c = threadIdx.x, r0 = threadIdx.y;
#pragma unroll
    for (int i = 0; i < 32; i += 8)
        t[r0 + i][c] = src[(size_t)(k0 + r0 + i) * N + n0 + c];
    __syncthreads();
#pragma unroll
    for (int i = 0; i < 32; i += 8)
        dst[(size_t)(n0 + r0 + i) * K + k0 + c] = f2bf(t[c][r0 + i]);
}

// ---------------------------------------------------------------------------
// Merged prep: [0,4096) attention-bias u8 quantization,
// [4096,4608) cast nf -> bf16, [4608,4632) fused qkv bias.
// ---------------------------------------------------------------------------
__global__ __launch_bounds__(256) void prep_k(
    const int* __restrict__ et, const int* __restrict__ sp,
    const float* __restrict__ ee, const float* __restrict__ de,
    unsigned char* __restrict__ biasT8,
    const float* __restrict__ nf, short* __restrict__ nfb,
    const float* __restrict__ qb, const float* __restrict__ kb,
    const float* __restrict__ vb, float* __restrict__ biasf)
{
    const int bid = blockIdx.x;
    const int tid = threadIdx.x;
    if (bid >= 4096) {
        if (bid < 4608) {
            const int i = (((bid - 4096) << 8) + tid) << 2;
            const float4 v = *(const float4*)(nf + i);
            *(short4*)(nfb + i) =
                make_short4(f2bf(v.x), f2bf(v.y), f2bf(v.z), f2bf(v.w));
        } else {
            const int i = ((bid - 4608) << 8) + tid;
            const int l = i / 1536, c = i % 1536;
            float v;
            if (c < 512)       v = qb[l * 512 + c];
            else if (c < 1024) v = kb[l * 512 + c - 512];
            else               v = vb[l * 512 + c - 1024];
            biasf[i] = v;
        }
        return;
    }
    __shared__ float eeS[16][8], deS[21][8];
    if (tid < 128) eeS[tid >> 3][tid & 7] = ee[tid];
    for (int t = tid; t < 168; t += 256)
        deS[t >> 3][t & 7] = de[t];
    __syncthreads();
    const int gid = bid * 256 + tid;             // over B*T*T/4
    const int j4  = (gid & 255) << 2;
    const int bi  = gid >> 8;                    // b*T + i
    const size_t base = (size_t)bi * T_ + j4;
    const int4 e = *(const int4*)(et + base);
    const int4 s = *(const int4*)(sp + base);
    const int b = bi >> 10, i = bi & 1023;
    const int ex[4] = {e.x, e.y, e.z, e.w};
    const int sx[4] = {min(s.x, 20), min(s.y, 20), min(s.z, 20), min(s.w, 20)};
#pragma unroll
    for (int h = 0; h < 8; ++h) {
        uchar4 o;
        float v;
        v = (eeS[ex[0]][h] + deS[sx[0]][h]) * LOG2E_ + 0.5f;
        o.x = (unsigned char)(int)fminf(fmaxf(v * 255.f + 0.5f, 0.f), 255.f);
        v = (eeS[ex[1]][h] + deS[sx[1]][h]) * LOG2E_ + 0.5f;
        o.y = (unsigned char)(int)fminf(fmaxf(v * 255.f + 0.5f, 0.f), 255.f);
        v = (eeS[ex[2]][h] + deS[sx[2]][h]) * LOG2E_ + 0.5f;
        o.z = (unsigned char)(int)fminf(fmaxf(v * 255.f + 0.5f, 0.f), 255.f);
        v = (eeS[ex[3]][h] + deS[sx[3]][h]) * LOG2E_ + 0.5f;
        o.w = (unsigned char)(int)fminf(fmaxf(v * 255.f + 0.5f, 0.f), 255.f);
        *(uchar4*)(biasT8 + ((size_t)((b * H_ + h) * T_ + i)) * T_ + j4) = o;
    }
}

// ---------------------------------------------------------------------------
// Embedding as MFMA GEMM, 128x64 tile, K=128. 4-buffer counted-vmcnt pipe.
// 1-D grid 256, XCD-swizzled decode (x8, y32).
// ---------------------------------------------------------------------------
__global__ __launch_bounds__(256) void embed_mm_k(
    const short* __restrict__ A, const short* __restrict__ Wt,
    const float* __restrict__ nb, const float* __restrict__ cb,
    const float* __restrict__ cW, const float* __restrict__ cent,
    float* __restrict__ C)
{
    const int K = F_, N = D_;
    __shared__ short As[4][128 * 32];
    __shared__ short Bs[4][64 * 32];
    const int tid  = threadIdx.x;
    const int lane = tid & 63, wv = tid >> 6;
    const int lb = blockIdx.x;
    const int xcd = lb & 7, jj = lb >> 3;            // jj in 0..31
    const int bx = jj & 7, by = (xcd << 2) + (jj >> 3);
    const int bm = by << 7, bn = bx << 6;
    const int wm = (wv & 1) << 6, wn = (wv >> 1) << 5;

    const int c0 = (wv << 6) + lane;
    const int m0 = c0 >> 2, q0 = (c0 & 3) ^ ((m0 >> 1) & 3);
    const int c1 = 256 + c0;
    const int m1 = c1 >> 2, q1 = (c1 & 3) ^ ((m1 >> 1) & 3);

    const short* gA0 = A  + (size_t)(bm + m0) * K + (q0 << 3);
    const short* gA1 = A  + (size_t)(bm + m1) * K + (q1 << 3);
    const short* gB0 = Wt + (size_t)(bn + m0) * K + (q0 << 3);

    f32x4 acc[4][2];
#pragma unroll
    for (int i = 0; i < 4; ++i)
#pragma unroll
        for (int j = 0; j < 2; ++j)
            acc[i][j] = (f32x4){0.f, 0.f, 0.f, 0.f};

    const int fm = lane & 15, fq = lane >> 4;
    int caddr[4], baddr[2];
#pragma unroll
    for (int t = 0; t < 4; ++t) {
        const int rowA = wm + (t << 4) + fm;
        caddr[t] = ((rowA << 2) + (fq ^ ((rowA >> 1) & 3))) << 3;
    }
#pragma unroll
    for (int t = 0; t < 2; ++t) {
        const int rowB = wn + (t << 4) + fm;
        baddr[t] = ((rowB << 2) + (fq ^ ((rowB >> 1) & 3))) << 3;
    }

#define EMB_STAGE(KK, BUF) do { \
    __builtin_amdgcn_global_load_lds(AS1(gA0 + (KK)), AS3(&As[BUF][(wv << 9)]),        16, 0, 0); \
    __builtin_amdgcn_global_load_lds(AS1(gA1 + (KK)), AS3(&As[BUF][2048 + (wv << 9)]), 16, 0, 0); \
    __builtin_amdgcn_global_load_lds(AS1(gB0 + (KK)), AS3(&Bs[BUF][(wv << 9)]),        16, 0, 0); \
} while (0)

    EMB_STAGE(0, 0); EMB_STAGE(32, 1); EMB_STAGE(64, 2);
    const int nt = K >> 5;                           // 4
    for (int t = 0; t < nt; ++t) {
        const int rem = nt - 1 - t;
        PIPE_BARRIER(rem, 6, 3);
        if (rem >= 3) EMB_STAGE((t + 3) << 5, (t + 3) & 3);
        const short* Asc = As[t & 3];
        const short* Bsc = Bs[t & 3];
        bf16x8 af[4], bf[2];
#pragma unroll
        for (int u = 0; u < 4; ++u) af[u] = *(const bf16x8*)(Asc + caddr[u]);
#pragma unroll
        for (int u = 0; u < 2; ++u) bf[u] = *(const bf16x8*)(Bsc + baddr[u]);
#pragma unroll
        for (int i = 0; i < 4; ++i)
#pragma unroll
            for (int j = 0; j < 2; ++j)
                acc[i][j] = __builtin_amdgcn_mfma_f32_16x16x32_bf16(
                    af[i], bf[j], acc[i][j], 0, 0, 0);
    }
#undef EMB_STAGE

    const int col0 = bn + wn + fm;
    const int row0 = bm + wm + (fq << 2);
#pragma unroll
    for (int j = 0; j < 2; ++j) {
        const int colg = col0 + (j << 4);
        const float bb = nb[colg] + cb[colg];
        const float cw = cW[colg];
#pragma unroll
        for (int i = 0; i < 4; ++i) {
#pragma unroll
            for (int r = 0; r < 4; ++r) {
                const int rowg = row0 + (i << 4) + r;
                C[(size_t)rowg * N + colg] = acc[i][j][r] + bb + cent[rowg] * cw;
            }
        }
    }
}

// ---------------------------------------------------------------------------
// bf16 MFMA GEMM, 128x128 tile: C = act(A @ Wt^T + bias) (+R)
// 4-buffer counted-vmcnt pipeline. 1-D grid, XCD decode for N=2048 (x16,y32).
// ---------------------------------------------------------------------------
template <int OUTM, int ACT, int RES>
__global__ __launch_bounds__(256) void mm_k(
    const short* __restrict__ A, const short* __restrict__ Wt,
    const float* __restrict__ bias, const float* __restrict__ R,
    void* __restrict__ Cv, int M, int N, int K)
{
    __shared__ short As[4][128 * 32];
    __shared__ short Bs[4][128 * 32];
    const int tid  = threadIdx.x;
    const int lane = tid & 63, wv = tid >> 6;
    const int lb = blockIdx.x;
    const int xcd = lb & 7, jj = lb >> 3;            // jj in 0..63
    const int bx = jj & 15, by = (xcd << 2) + (jj >> 4);
    const int bm = by << 7, bn = bx << 7;
    const int wm = (wv & 1) << 6, wn = (wv >> 1) << 6;

    const int c0 = (wv << 6) + lane;
    const int m0 = c0 >> 2, q0 = (c0 & 3) ^ ((m0 >> 1) & 3);
    const int c1 = 256 + c0;
    const int m1 = c1 >> 2, q1 = (c1 & 3) ^ ((m1 >> 1) & 3);

    const short* gA0 = A  + (size_t)(bm + m0) * K + (q0 << 3);
    const short* gA1 = A  + (size_t)(bm + m1) * K + (q1 << 3);
    const short* gB0 = Wt + (size_t)(bn + m0) * K + (q0 << 3);
    const short* gB1 = Wt + (size_t)(bn + m1) * K + (q1 << 3);

    f32x4 acc[4][4];
#pragma unroll
    for (int i = 0; i < 4; ++i)
#pragma unroll
        for (int j = 0; j < 4; ++j)
            acc[i][j] = (f32x4){0.f, 0.f, 0.f, 0.f};

    const int fm = lane & 15, fq = lane >> 4;
    int caddr[4], baddr[4];
#pragma unroll
    for (int t = 0; t < 4; ++t) {
        const int rowA = wm + (t << 4) + fm;
        caddr[t] = ((rowA << 2) + (fq ^ ((rowA >> 1) & 3))) << 3;
        const int rowB = wn + (t << 4) + fm;
        baddr[t] = ((rowB << 2) + (fq ^ ((rowB >> 1) & 3))) << 3;
    }

#define MM_STAGE(KK, BUF) do { \
    __builtin_amdgcn_global_load_lds(AS1(gA0 + (KK)), AS3(&As[BUF][(wv << 9)]),        16, 0, 0); \
    __builtin_amdgcn_global_load_lds(AS1(gA1 + (KK)), AS3(&As[BUF][2048 + (wv << 9)]), 16, 0, 0); \
    __builtin_amdgcn_global_load_lds(AS1(gB0 + (KK)), AS3(&Bs[BUF][(wv << 9)]),        16, 0, 0); \
    __builtin_amdgcn_global_load_lds(AS1(gB1 + (KK)), AS3(&Bs[BUF][2048 + (wv << 9)]), 16, 0, 0); \
} while (0)

    MM_STAGE(0, 0); MM_STAGE(32, 1); MM_STAGE(64, 2);
    const int nt = K >> 5;
    for (int t = 0; t < nt; ++t) {
        const int rem = nt - 1 - t;
        PIPE_BARRIER(rem, 8, 4);
        if (rem >= 3) MM_STAGE((t + 3) << 5, (t + 3) & 3);
        const short* Asc = As[t & 3];
        const short* Bsc = Bs[t & 3];
        bf16x8 af[4], bf[4];
#pragma unroll
        for (int u = 0; u < 4; ++u) {
            af[u] = *(const bf16x8*)(Asc + caddr[u]);
            bf[u] = *(const bf16x8*)(Bsc + baddr[u]);
        }
#pragma unroll
        for (int i = 0; i < 4; ++i)
#pragma unroll
            for (int j = 0; j < 4; ++j)
                acc[i][j] = __builtin_amdgcn_mfma_f32_16x16x32_bf16(
                    af[i], bf[j], acc[i][j], 0, 0, 0);
    }
#undef MM_STAGE

    const int col0 = bn + wn + fm;
    const int row0 = bm + wm + (fq << 2);
    float* Cf = (float*)Cv;
    short* Cb = (short*)Cv;
#pragma unroll
    for (int j = 0; j < 4; ++j) {
        const int colg = col0 + (j << 4);
        const float bb = bias[colg];
#pragma unroll
        for (int i = 0; i < 4; ++i) {
#pragma unroll
            for (int r = 0; r < 4; ++r) {
                const int rowg = row0 + (i << 4) + r;
                float v = acc[i][j][r] + bb;
                if (ACT) v = v / (1.f + __expf(-v));
                const size_t off = (size_t)rowg * N + colg;
                if (RES) v += R[off];
                if (OUTM == 1) Cb[off] = f2bf(v);
                else           Cf[off] = v;
            }
        }
    }
}

// ---------------------------------------------------------------------------
// QKV GEMM, 128x64 tile. N=1536 fixed. 4-buffer counted-vmcnt pipeline.
// 1-D grid 768, XCD decode (x24, y32).
// Q,K -> QKb [M][1024]; V -> Vt [B*H][64][T] (transposed scatter).
// ---------------------------------------------------------------------------
__global__ __launch_bounds__(256) void qkv64_k(
    const short* __restrict__ A, const short* __restrict__ Wt,
    const float* __restrict__ bias, short* __restrict__ QKb,
    short* __restrict__ VtOut)
{
    const int K = D_;
    __shared__ short As[4][128 * 32];
    __shared__ short Bs[4][64 * 32];
    const int tid  = threadIdx.x;
    const int lane = tid & 63, wv = tid >> 6;
    const int lb = blockIdx.x;
    const int xcd = lb & 7, jj = lb >> 3;            // jj in 0..95
    const int yl = jj / 24, bx = jj - yl * 24;
    const int by = (xcd << 2) + yl;
    const int bm = by << 7, bn = bx << 6;
    const int wm = (wv & 1) << 6, wn = (wv >> 1) << 5;

    const int c0 = (wv << 6) + lane;
    const int m0 = c0 >> 2, q0 = (c0 & 3) ^ ((m0 >> 1) & 3);
    const int c1 = 256 + c0;
    const int m1 = c1 >> 2, q1 = (c1 & 3) ^ ((m1 >> 1) & 3);

    const short* gA0 = A  + (size_t)(bm + m0) * K + (q0 << 3);
    const short* gA1 = A  + (size_t)(bm + m1) * K + (q1 << 3);
    const short* gB0 = Wt + (size_t)(bn + m0) * K + (q0 << 3);

    f32x4 acc[4][2];
#pragma unroll
    for (int i = 0; i < 4; ++i)
#pragma unroll
        for (int j = 0; j < 2; ++j)
            acc[i][j] = (f32x4){0.f, 0.f, 0.f, 0.f};

    const int fm = lane & 15, fq = lane >> 4;
    int caddr[4], baddr[2];
#pragma unroll
    for (int t = 0; t < 4; ++t) {
        const int rowA = wm + (t << 4) + fm;
        caddr[t] = ((rowA << 2) + (fq ^ ((rowA >> 1) & 3))) << 3;
    }
#pragma unroll
    for (int t = 0; t < 2; ++t) {
        const int rowB = wn + (t << 4) + fm;
        baddr[t] = ((rowB << 2) + (fq ^ ((rowB >> 1) & 3))) << 3;
    }

#define QKV_STAGE(KK, BUF) do { \
    __builtin_amdgcn_global_load_lds(AS1(gA0 + (KK)), AS3(&As[BUF][(wv << 9)]),        16, 0, 0); \
    __builtin_amdgcn_global_load_lds(AS1(gA1 + (KK)), AS3(&As[BUF][2048 + (wv << 9)]), 16, 0, 0); \
    __builtin_amdgcn_global_load_lds(AS1(gB0 + (KK)), AS3(&Bs[BUF][(wv << 9)]),        16, 0, 0); \
} while (0)

    QKV_STAGE(0, 0); QKV_STAGE(32, 1); QKV_STAGE(64, 2);
    const int nt = K >> 5;
    for (int t = 0; t < nt; ++t) {
        const int rem = nt - 1 - t;
        PIPE_BARRIER(rem, 6, 3);
        if (rem >= 3) QKV_STAGE((t + 3) << 5, (t + 3) & 3);
        const short* Asc = As[t & 3];
        const short* Bsc = Bs[t & 3];
        bf16x8 af[4], bf[2];
#pragma unroll
        for (int u = 0; u < 4; ++u) af[u] = *(const bf16x8*)(Asc + caddr[u]);
#pragma unroll
        for (int u = 0; u < 2; ++u) bf[u] = *(const bf16x8*)(Bsc + baddr[u]);
#pragma unroll
        for (int i = 0; i < 4; ++i)
#pragma unroll
            for (int j = 0; j < 2; ++j)
                acc[i][j] = __builtin_amdgcn_mfma_f32_16x16x32_bf16(
                    af[i], bf[j], acc[i][j], 0, 0, 0);
    }
#undef QKV_STAGE

    const int col0 = bn + wn + fm;
    const int row0 = bm + wm + (fq << 2);
#pragma unroll
    for (int j = 0; j < 2; ++j) {
        const int colg = col0 + (j << 4);
        const float bb = bias[colg];
#pragma unroll
        for (int i = 0; i < 4; ++i) {
#pragma unroll
            for (int r = 0; r < 4; ++r) {
                const int rowg = row0 + (i << 4) + r;
                const float v = acc[i][j][r] + bb;
                if (colg < 1024) {
                    QKb[(size_t)rowg * 1024 + colg] = f2bf(v);
                } else {
                    const int da = colg - 1024;
                    const int hh = da >> 6, dd = da & 63;
                    const int bb2 = rowg >> 10, tt = rowg & 1023;
                    VtOut[((size_t)(bb2 * H_ + hh) * 64 + dd) * T_ + tt] = f2bf(v);
                }
            }
        }
    }
}

// ---------------------------------------------------------------------------
// MFMA flash attention v3.2 (single-buffered; 29 KB LDS, 4 blocks/CU).
// grid (2*T/64, H, B), 256 threads = 4 waves.
// ---------------------------------------------------------------------------
__global__ __launch_bounds__(256) void flash_k(
    const short* __restrict__ QKb, const short* __restrict__ Vt,
    const unsigned char* __restrict__ biasT8, short* __restrict__ OpartB,
    float* __restrict__ Lpart)
{
    const int tid = threadIdx.x;
    const int bx = blockIdx.x;
    const int it = bx >> 1, split = bx & 1;
    const int i0 = it << 6;
    const int h  = blockIdx.y;
    const int b  = blockIdx.z;
    const int lane = tid & 63, w = tid >> 6;
    const int fm = lane & 15, q = lane >> 4;

    __shared__ short Ks[4096];          // 64 rows x 8 chunks(16B), chunk ^= row&7
    __shared__ short Vs[4096];
    __shared__ unsigned char Bsh8[4096]; // 64 rows x 4 chunks(16B), chunk ^= row&3
    __shared__ short Ps[64][72];

    const short* qp = QKb + (size_t)(b * T_ + i0 + (w << 4) + fm) * 1024 + (h << 6) + (q << 3);
    const bf16x8 aq0 = *(const bf16x8*)(qp);
    const bf16x8 aq1 = *(const bf16x8*)(qp + 32);

    const int s0 = (w << 6) + lane, r0 = s0 >> 3, cc0 = (s0 & 7) ^ (r0 & 7);
    const int s1 = 256 + s0,        r1 = s1 >> 3, cc1 = (s1 & 7) ^ (r1 & 7);
    const short* gK0 = QKb + (size_t)(b * T_ + r0) * 1024 + 512 + (h << 6) + (cc0 << 3);
    const short* gK1 = QKb + (size_t)(b * T_ + r1) * 1024 + 512 + (h << 6) + (cc1 << 3);
    const short* gV0 = Vt + ((size_t)((b * H_ + h) << 6) + r0) * T_ + (cc0 << 3);
    const short* gV1 = Vt + ((size_t)((b * H_ + h) << 6) + r1) * T_ + (cc1 << 3);
    // u8 bias tile: 256 chunks of 16B; slot s0 -> row s0>>2, chunk (s0&3)^(row&3)
    const int br = s0 >> 2, bc = (s0 & 3) ^ (br & 3);
    const unsigned char* gB0 = biasT8 +
        ((size_t)(b * H_ + h) * T_ + i0 + br) * T_ + (bc << 4);

    int fAddr[4][2];
#pragma unroll
    for (int t = 0; t < 4; ++t) {
        const int row = (t << 4) + fm;
#pragma unroll
        for (int ks = 0; ks < 2; ++ks)
            fAddr[t][ks] = (row << 6) + (((q + (ks << 2)) ^ (row & 7)) << 3);
    }

    // u8 bias LDS read addrs
    int bAddr[4][4];
#pragma unroll
    for (int r = 0; r < 4; ++r) {
        const int rowL = (w << 4) + (q << 2) + r;
#pragma unroll
        for (int jt = 0; jt < 4; ++jt)
            bAddr[r][jt] = (rowL << 6) + (((jt ^ (rowL & 3))) << 4) + fm;
    }

    const short oneb = 0x3F80;                   // bf16 1.0
    const bf16x8 ones = {oneb, oneb, oneb, oneb, oneb, oneb, oneb, oneb};

    f32x4 accO[4];
#pragma unroll
    for (int dt = 0; dt < 4; ++dt) accO[dt] = (f32x4){0.f, 0.f, 0.f, 0.f};
    f32x4 accL = (f32x4){0.f, 0.f, 0.f, 0.f};

    const int irow = b * T_ + i0 + (w << 4) + (q << 2);
    short* psW = &Ps[(w << 4) + (q << 2)][fm];
    const short* psR = &Ps[(w << 4) + fm][q << 3];

    const int jbeg = split << 9, jend = jbeg + 512;
    for (int j0 = jbeg; j0 < jend; j0 += 64) {
        __syncthreads();
        __builtin_amdgcn_global_load_lds(AS1(gK0 + (size_t)j0 * 1024), AS3(Ks + (s0 << 3)), 16, 0, 0);
        __builtin_amdgcn_global_load_lds(AS1(gK1 + (size_t)j0 * 1024), AS3(Ks + (s1 << 3)), 16, 0, 0);
        __builtin_amdgcn_global_load_lds(AS1(gV0 + j0), AS3(Vs + (s0 << 3)), 16, 0, 0);
        __builtin_amdgcn_global_load_lds(AS1(gV1 + j0), AS3(Vs + (s1 << 3)), 16, 0, 0);
        __builtin_amdgcn_global_load_lds(AS1(gB0 + j0), AS3(Bsh8 + (s0 << 4)), 16, 0, 0);
        __syncthreads();

        f32x4 s[4];
#pragma unroll
        for (int jt = 0; jt < 4; ++jt) s[jt] = (f32x4){0.f, 0.f, 0.f, 0.f};
#pragma unroll
        for (int jt = 0; jt < 4; ++jt) {
            const bf16x8 k0 = *(const bf16x8*)(Ks + fAddr[jt][0]);
            const bf16x8 k1 = *(const bf16x8*)(Ks + fAddr[jt][1]);
            s[jt] = __builtin_amdgcn_mfma_f32_16x16x32_bf16(aq0, k0, s[jt], 0, 0, 0);
            s[jt] = __builtin_amdgcn_mfma_f32_16x16x32_bf16(aq1, k1, s[jt], 0, 0, 0);
        }

        // P = 2^(s*scale*log2e + (q8/255 - 0.5)) — fixed max, direct to LDS
#pragma unroll
        for (int r = 0; r < 4; ++r)
#pragma unroll
            for (int jt = 0; jt < 4; ++jt) {
                const float q8 = (float)Bsh8[bAddr[r][jt]];
                const float bb = fmaf(q8, 1.f / 255.f, -0.5f);
                const float p = __builtin_amdgcn_exp2f(fmaf(s[jt][r], CL2E_, bb));
                psW[(size_t)r * 72 + (jt << 4)] = f2bf(p);
            }

        // O += P V ; l += P @ ones (MFMA row-sum)
#pragma unroll
        for (int ks = 0; ks < 2; ++ks) {
            const bf16x8 ap = *(const bf16x8*)(psR + (ks << 5));
            accL = __builtin_amdgcn_mfma_f32_16x16x32_bf16(ap, ones, accL, 0, 0, 0);
#pragma unroll
            for (int dt = 0; dt < 4; ++dt) {
                const bf16x8 bv = *(const bf16x8*)(Vs + fAddr[dt][ks]);
                accO[dt] = __builtin_amdgcn_mfma_f32_16x16x32_bf16(ap, bv, accO[dt], 0, 0, 0);
            }
        }
    }

    short* obase = OpartB + (size_t)split * B_ * T_ * D_;
#pragma unroll
    for (int r = 0; r < 4; ++r) {
        short* op = obase + (size_t)(irow + r) * D_ + (h << 6) + fm;
#pragma unroll
        for (int dt = 0; dt < 4; ++dt)
            op[dt << 4] = f2bf(accO[dt][r]);
    }
    if (fm == 0) {
#pragma unroll
        for (int r = 0; r < 4; ++r)
            Lpart[(size_t)split * B_ * T_ * H_ + (size_t)(irow + r) * H_ + h] = accL[r];
    }
}

// ---------------------------------------------------------------------------
// Combine split-K attention partials: Ob = bf16((O0+O1) / (l0+l1))
// ---------------------------------------------------------------------------
__global__ __launch_bounds__(256) void combine_k(
    const short* __restrict__ OpartB, const float* __restrict__ Lpart,
    short* __restrict__ Ob)
{
    const int gid = blockIdx.x * 256 + threadIdx.x;   // over M*D/4
    const int d4  = (gid & 127) << 2;
    const int row = gid >> 7;
    const int h   = d4 >> 6;
    const float l = Lpart[(size_t)row * H_ + h] +
                    Lpart[(size_t)B_ * T_ * H_ + (size_t)row * H_ + h];
    const float inv = 1.f / l;
    const size_t o = (size_t)row * D_ + d4;
    const short4 a = *(const short4*)(OpartB + o);
    const short4 c = *(const short4*)(OpartB + (size_t)B_ * T_ * D_ + o);
    short4 r = make_short4(
        f2bf((bf2f(a.x) + bf2f(c.x)) * inv), f2bf((bf2f(a.y) + bf2f(c.y)) * inv),
        f2bf((bf2f(a.z) + bf2f(c.z)) * inv), f2bf((bf2f(a.w) + bf2f(c.w)) * inv));
    *(short4*)(Ob + o) = r;
}

// ---------------------------------------------------------------------------
// bf16 MFMA GEMM, 128x64 tile, N=512. fp32 out + residual.
// 4-buffer counted-vmcnt pipeline; 1-D grid 256, XCD decode (x8, y32):
// each XCD owns 4 full M-panels -> A-panel re-reads hit its own L2.
// ---------------------------------------------------------------------------
__global__ __launch_bounds__(256) void mm64_k(
    const short* __restrict__ A, const short* __restrict__ Wt,
    const float* __restrict__ bias, const float* __restrict__ R,
    float* __restrict__ C, int M, int N, int K)
{
    __shared__ short As[4][128 * 32];
    __shared__ short Bs[4][64 * 32];
    const int tid  = threadIdx.x;
    const int lane = tid & 63, wv = tid >> 6;
    const int lb = blockIdx.x;
    const int xcd = lb & 7, jj = lb >> 3;            // jj in 0..31
    const int bx = jj & 7, by = (xcd << 2) + (jj >> 3);
    const int bm = by << 7, bn = bx << 6;
    const int wm = (wv & 1) << 6, wn = (wv >> 1) << 5;

    const int c0 = (wv << 6) + lane;
    const int m0 = c0 >> 2, q0 = (c0 & 3) ^ ((m0 >> 1) & 3);
    const int c1 = 256 + c0;
    const int m1 = c1 >> 2, q1 = (c1 & 3) ^ ((m1 >> 1) & 3);

    const short* gA0 = A  + (size_t)(bm + m0) * K + (q0 << 3);
    const short* gA1 = A  + (size_t)(bm + m1) * K + (q1 << 3);
    const short* gB0 = Wt + (size_t)(bn + m0) * K + (q0 << 3);

    f32x4 acc[4][2];
#pragma unroll
    for (int i = 0; i < 4; ++i)
#pragma unroll
        for (int j = 0; j < 2; ++j)
            acc[i][j] = (f32x4){0.f, 0.f, 0.f, 0.f};

    const int fm = lane & 15, fq = lane >> 4;
    int caddr[4], baddr[2];
#pragma unroll
    for (int t = 0; t < 4; ++t) {
        const int rowA = wm + (t << 4) + fm;
        caddr[t] = ((rowA << 2) + (fq ^ ((rowA >> 1) & 3))) << 3;
    }
#pragma unroll
    for (int t = 0; t < 2; ++t) {
        const int rowB = wn + (t << 4) + fm;
        baddr[t] = ((rowB << 2) + (fq ^ ((rowB >> 1) & 3))) << 3;
    }

#define MM64_STAGE(KK, BUF) do { \
    __builtin_amdgcn_global_load_lds(AS1(gA0 + (KK)), AS3(&As[BUF][(wv << 9)]),        16, 0, 0); \
    __builtin_amdgcn_global_load_lds(AS1(gA1 + (KK)), AS3(&As[BUF][2048 + (wv << 9)]), 16, 0, 0); \
    __builtin_amdgcn_global_load_lds(AS1(gB0 + (KK)), AS3(&Bs[BUF][(wv << 9)]),        16, 0, 0); \
} while (0)

    MM64_STAGE(0, 0); MM64_STAGE(32, 1); MM64_STAGE(64, 2);
    const int nt = K >> 5;
    for (int t = 0; t < nt; ++t) {
        const int rem = nt - 1 - t;
        PIPE_BARRIER(rem, 6, 3);
        if (rem >= 3) MM64_STAGE((t + 3) << 5, (t + 3) & 3);
        const short* Asc = As[t & 3];
        const short* Bsc = Bs[t & 3];
        bf16x8 af[4], bf[2];
#pragma unroll
        for (int u = 0; u < 4; ++u) af[u] = *(const bf16x8*)(Asc + caddr[u]);
#pragma unroll
        for (int u = 0; u < 2; ++u) bf[u] = *(const bf16x8*)(Bsc + baddr[u]);
#pragma unroll
        for (int i = 0; i < 4; ++i)
#pragma unroll
            for (int j = 0; j < 2; ++j)
                acc[i][j] = __builtin_amdgcn_mfma_f32_16x16x32_bf16(
                    af[i], bf[j], acc[i][j], 0, 0, 0);
    }
#undef MM64_STAGE

    const int col0 = bn + wn + fm;
    const int row0 = bm + wm + (fq << 2);
#pragma unroll
    for (int j = 0; j < 2; ++j) {
        const int colg = col0 + (j << 4);
        const float bb = bias[colg];
#pragma unroll
        for (int i = 0; i < 4; ++i) {
#pragma unroll
            for (int r = 0; r < 4; ++r) {
                const int rowg = row0 + (i << 4) + r;
                const size_t off = (size_t)rowg * N + colg;
                C[off] = acc[i][j][r] + bb + R[off];
            }
        }
    }
}

// ---------------------------------------------------------------------------
extern "C" void kernel_launch(void* const* d_in, const int* in_sizes, int n_in,
                              void* d_out, int out_size, void* d_ws, size_t ws_size,
                              hipStream_t stream)
{
    (void)in_sizes; (void)n_in; (void)out_size; (void)ws_size;

    const float* nf   = (const float*)d_in[0];
    const float* cent = (const float*)d_in[1];
    const int*   et   = (const int*)  d_in[2];
    const int*   sp   = (const int*)  d_in[3];
    const float* nW   = (const float*)d_in[4];
    const float* nb   = (const float*)d_in[5];
    const float* cW   = (const float*)d_in[6];
    const float* cb   = (const float*)d_in[7];
    const float* ee   = (const float*)d_in[8];
    const float* de   = (const float*)d_in[9];
    const float* ln1w = (const float*)d_in[10];
    const float* ln1b = (const float*)d_in[11];
    const float* qW   = (const float*)d_in[12];
    const float* qb   = (const float*)d_in[13];
    const float* kW   = (const float*)d_in[14];
    const float* kb   = (const float*)d_in[15];
    const float* vW   = (const float*)d_in[16];
    const float* vb   = (const float*)d_in[17];
    const float* oW   = (const float*)d_in[18];
    const float* ob   = (const float*)d_in[19];
    const float* ln2w = (const float*)d_in[20];
    const float* ln2b = (const float*)d_in[21];
    const float* f1W  = (const float*)d_in[22];
    const float* f1b  = (const float*)d_in[23];
    const float* f2W  = (const float*)d_in[24];
    const float* f2b  = (const float*)d_in[25];

    const int M = B_ * T_;                          // 4096
    char* p = (char*)d_ws;
    float* Hbuf  = (float*)p;  p += (size_t)M * D_ * 4;                    // 8 MB
    short* QKb   = (short*)p;  p += (size_t)M * 1024 * 2;                  // 8 MB
    short* Vt    = (short*)p;  p += (size_t)B_ * H_ * 64 * T_ * 2;         // 4 MB
    float* biasf = (float*)p;  p += (size_t)L_ * 3 * D_ * 4;               // 24 KB
    short* Xbuf  = (short*)p;  p += (size_t)M * D_ * 2;                    // 4 MB
    short* Ob    = (short*)p;  p += (size_t)M * D_ * 2;                    // 4 MB
    short* FF    = (short*)p;  p += (size_t)M * DFF_ * 2;                  // 16 MB
    unsigned char* biasT8 = (unsigned char*)p; p += (size_t)B_ * H_ * T_ * T_; // 33.5 MB
    short* WqkvT = (short*)p;  p += (size_t)L_ * 3 * D_ * D_ * 2;
    short* WoT   = (short*)p;  p += (size_t)L_ * D_ * D_ * 2;
    short* Wf1T  = (short*)p;  p += (size_t)L_ * DFF_ * D_ * 2;
    short* Wf2T  = (short*)p;  p += (size_t)L_ * D_ * DFF_ * 2;
    short* nfb   = (short*)p;  p += (size_t)M * F_ * 2;                    // 1 MB
    short* nWt   = (short*)p;  p += (size_t)D_ * F_ * 2;                   // 128 KB
    short* OpartB = (short*)p; p += (size_t)2 * M * D_ * 2;                // 8 MB
    float* Lpart = (float*)p;  p += (size_t)2 * M * H_ * 4;                // 256 KB

    float* out = (float*)d_out;

    // ---- prep (3 dispatches)
    transpose_all_k<<<dim3(1024, 25), dim3(32, 8), 0, stream>>>(
        qW, kW, vW, oW, f1W, f2W, nW, WqkvT, WoT, Wf1T, Wf2T, nWt);
    prep_k<<<dim3(4632), dim3(256), 0, stream>>>(
        et, sp, ee, de, biasT8, nf, nfb, qb, kb, vb, biasf);
    embed_mm_k<<<dim3(256), dim3(256), 0, stream>>>(
        nfb, nWt, nb, cb, cW, cent, Hbuf);

    const dim3 blk(256);
    const dim3 gQKV(768);                     // 1-D, XCD decode inside
    const dim3 gO64(256);
    const dim3 gF1 (512);
    const dim3 gAttn(2 * T_ / 64, H_, B_);    // (32, 8, 4) = 1024 blocks
    const dim3 gCmb(M * D_ / 1024);           // 2048 blocks

    for (int l = 0; l < L_; ++l) {
        const size_t bOff  = (size_t)l * D_;
        const size_t b1Off = (size_t)l * DFF_;

        ln_k<<<dim3(M), blk, 0, stream>>>(Hbuf, ln1w + bOff, ln1b + bOff, Xbuf);

        qkv64_k<<<gQKV, blk, 0, stream>>>(
            Xbuf, WqkvT + (size_t)l * 3 * D_ * D_, biasf + (size_t)l * 3 * D_,
            QKb, Vt);

        flash_k<<<gAttn, blk, 0, stream>>>(QKb, Vt, biasT8, OpartB, Lpart);
        combine_k<<<gCmb, blk, 0, stream>>>(OpartB, Lpart, Ob);

        mm64_k<<<gO64, blk, 0, stream>>>(
            Ob, WoT + (size_t)l * D_ * D_, ob + bOff, Hbuf, Hbuf, M, D_, D_);

        ln_k<<<dim3(M), blk, 0, stream>>>(Hbuf, ln2w + bOff, ln2b + bOff, Xbuf);

        mm_k<1, 1, 0><<<gF1, blk, 0, stream>>>(
            Xbuf, Wf1T + (size_t)l * DFF_ * D_, f1b + b1Off, nullptr, FF, M, DFF_, D_);

        float* cdst = (l == L_ - 1) ? out : Hbuf;
        mm64_k<<<gO64, blk, 0, stream>>>(
            FF, Wf2T + (size_t)l * D_ * DFF_, f2b + bOff, Hbuf, cdst, M, D_, DFF_);
    }
}

// Round 4
// 623.377 us; speedup vs baseline: 1.2662x; 1.0521x over previous
//
#include <hip/hip_runtime.h>
#include <cstddef>
#include <cstdint>

#define B_    4
#define T_    1024
#define F_    128
#define D_    512
#define H_    8
#define L_    4
#define DFF_  2048
#define HD_   64
#define SCALE_ 0.125f   // 1/sqrt(64)
#define LOG2E_ 1.4426950408889634f
#define CL2E_  (SCALE_ * LOG2E_)

typedef __attribute__((ext_vector_type(8))) short bf16x8;
typedef __attribute__((ext_vector_type(4))) float f32x4;

#define AS1(p) ((const __attribute__((address_space(1))) void*)(p))
#define AS3(p) ((__attribute__((address_space(3))) void*)(p))

__device__ __forceinline__ short f2bf(float f) {
    unsigned u = __float_as_uint(f);
    u += 0x7FFFu + ((u >> 16) & 1u);      // round-to-nearest-even
    return (short)(u >> 16);
}
__device__ __forceinline__ float bf2f(short s) {
    return __uint_as_float(((unsigned)(unsigned short)s) << 16);
}

// Counted-vmcnt pipeline barrier (T4): wait only for the OLDEST in-flight
// stage; keep 2 stages in flight across the barrier.
#define PIPE_BARRIER(rem, W2, W1)                                             \
    if ((rem) >= 2)      asm volatile("s_waitcnt vmcnt(" #W2 ")" ::: "memory"); \
    else if ((rem) == 1) asm volatile("s_waitcnt vmcnt(" #W1 ")" ::: "memory"); \
    else                 asm volatile("s_waitcnt vmcnt(0)"      ::: "memory"); \
    __builtin_amdgcn_s_barrier();                                             \
    __builtin_amdgcn_sched_barrier(0);

// ---------------------------------------------------------------------------
// LayerNorm, fp32 in -> bf16 out.
// NP=2: first folds the split-K GEMM reduction:  H = H + P0 + P1 (written
// back to X), then LayerNorms H. Replaces the GEMM's residual read-modify-
// write and kills a combine pass.
// ---------------------------------------------------------------------------
template <int NP>
__global__ __launch_bounds__(256) void ln_k(
    float* __restrict__ X, const float* __restrict__ P0,
    const float* __restrict__ P1, const float* __restrict__ w,
    const float* __restrict__ b, short* __restrict__ Y)
{
    const int row = blockIdx.x;
    const int tid = threadIdx.x;
    float* xr = X + (size_t)row * D_;
    float v0 = xr[tid];
    float v1 = xr[tid + 256];
    if (NP == 2) {
        const size_t o0 = (size_t)row * D_ + tid;
        const size_t o1 = o0 + 256;
        v0 += P0[o0] + P1[o0];
        v1 += P0[o1] + P1[o1];
        xr[tid]       = v0;
        xr[tid + 256] = v1;
    }
    float s  = v0 + v1;
    float s2 = v0 * v0 + v1 * v1;
#pragma unroll
    for (int off = 1; off < 64; off <<= 1) {
        s  += __shfl_xor(s,  off);
        s2 += __shfl_xor(s2, off);
    }
    __shared__ float ss[4], ss2[4];
    if ((tid & 63) == 0) { ss[tid >> 6] = s; ss2[tid >> 6] = s2; }
    __syncthreads();
    s  = ss[0]  + ss[1]  + ss[2]  + ss[3];
    s2 = ss2[0] + ss2[1] + ss2[2] + ss2[3];
    const float mean = s * (1.f / D_);
    const float var  = s2 * (1.f / D_) - mean * mean;
    const float r    = rsqrtf(var + 1e-5f);
    short* yr = Y + (size_t)row * D_;
    yr[tid]       = f2bf((v0 - mean) * r * w[tid]       + b[tid]);
    yr[tid + 256] = f2bf((v1 - mean) * r * w[tid + 256] + b[tid + 256]);
}

// ---------------------------------------------------------------------------
// Final reduction: out = H + P0 + P1  (fp32, vectorized)
// ---------------------------------------------------------------------------
__global__ __launch_bounds__(256) void red_k(
    const float* __restrict__ X, const float* __restrict__ P0,
    const float* __restrict__ P1, float* __restrict__ Dst)
{
    const int i = (blockIdx.x * 256 + threadIdx.x) << 2;
    const float4 a = *(const float4*)(X + i);
    const float4 p = *(const float4*)(P0 + i);
    const float4 q = *(const float4*)(P1 + i);
    *(float4*)(Dst + i) = make_float4(a.x + p.x + q.x, a.y + p.y + q.y,
                                      a.z + p.z + q.z, a.w + p.w + q.w);
}

// ---------------------------------------------------------------------------
// ALL weight transposes in one launch
// ---------------------------------------------------------------------------
__global__ __launch_bounds__(256) void transpose_all_k(
    const float* __restrict__ qW, const float* __restrict__ kW,
    const float* __restrict__ vW, const float* __restrict__ oW,
    const float* __restrict__ f1W, const float* __restrict__ f2W,
    const float* __restrict__ nW,
    short* __restrict__ WqkvT, short* __restrict__ WoT,
    short* __restrict__ Wf1T, short* __restrict__ Wf2T,
    short* __restrict__ nWt)
{
    const int id = blockIdx.y;
    const float* src; short* dst; int K, N;
    if (id < 12) {
        const int l = id / 3, which = id % 3;
        const float* s3 = (which == 0) ? qW : (which == 1) ? kW : vW;
        src = s3 + (size_t)l * D_ * D_;
        dst = WqkvT + ((size_t)l * 3 + which) * D_ * D_;
        K = D_; N = D_;
    } else if (id < 16) {
        const int l = id - 12;
        src = oW + (size_t)l * D_ * D_;  dst = WoT + (size_t)l * D_ * D_;
        K = D_; N = D_;
    } else if (id < 20) {
        const int l = id - 16;
        src = f1W + (size_t)l * D_ * DFF_;  dst = Wf1T + (size_t)l * DFF_ * D_;
        K = D_; N = DFF_;
    } else if (id < 24) {
        const int l = id - 20;
        src = f2W + (size_t)l * DFF_ * D_;  dst = Wf2T + (size_t)l * D_ * DFF_;
        K = DFF_; N = D_;
    } else {
        src = nW; dst = nWt; K = F_; N = D_;
    }
    const int ntiles = (K >> 5) * (N >> 5);
    if ((int)blockIdx.x >= ntiles) return;
    const int nt = N >> 5;
    const int k0 = (blockIdx.x / nt) << 5, n0 = (blockIdx.x % nt) << 5;

    __shared__ float t[32][33];
    const int c = threadIdx.x, r0 = threadIdx.y;
#pragma unroll
    for (int i = 0; i < 32; i += 8)
        t[r0 + i][c] = src[(size_t)(k0 + r0 + i) * N + n0 + c];
    __syncthreads();
#pragma unroll
    for (int i = 0; i < 32; i += 8)
        dst[(size_t)(n0 + r0 + i) * K + k0 + c] = f2bf(t[c][r0 + i]);
}

// ---------------------------------------------------------------------------
// Merged prep: [0,4096) attention-bias u8 quantization,
// [4096,4608) cast nf -> bf16, [4608,4632) fused qkv bias.
// ---------------------------------------------------------------------------
__global__ __launch_bounds__(256) void prep_k(
    const int* __restrict__ et, const int* __restrict__ sp,
    const float* __restrict__ ee, const float* __restrict__ de,
    unsigned char* __restrict__ biasT8,
    const float* __restrict__ nf, short* __restrict__ nfb,
    const float* __restrict__ qb, const float* __restrict__ kb,
    const float* __restrict__ vb, float* __restrict__ biasf)
{
    const int bid = blockIdx.x;
    const int tid = threadIdx.x;
    if (bid >= 4096) {
        if (bid < 4608) {
            const int i = (((bid - 4096) << 8) + tid) << 2;
            const float4 v = *(const float4*)(nf + i);
            *(short4*)(nfb + i) =
                make_short4(f2bf(v.x), f2bf(v.y), f2bf(v.z), f2bf(v.w));
        } else {
            const int i = ((bid - 4608) << 8) + tid;
            const int l = i / 1536, c = i % 1536;
            float v;
            if (c < 512)       v = qb[l * 512 + c];
            else if (c < 1024) v = kb[l * 512 + c - 512];
            else               v = vb[l * 512 + c - 1024];
            biasf[i] = v;
        }
        return;
    }
    __shared__ float eeS[16][8], deS[21][8];
    if (tid < 128) eeS[tid >> 3][tid & 7] = ee[tid];
    for (int t = tid; t < 168; t += 256)
        deS[t >> 3][t & 7] = de[t];
    __syncthreads();
    const int gid = bid * 256 + tid;             // over B*T*T/4
    const int j4  = (gid & 255) << 2;
    const int bi  = gid >> 8;                    // b*T + i
    const size_t base = (size_t)bi * T_ + j4;
    const int4 e = *(const int4*)(et + base);
    const int4 s = *(const int4*)(sp + base);
    const int b = bi >> 10, i = bi & 1023;
    const int ex[4] = {e.x, e.y, e.z, e.w};
    const int sx[4] = {min(s.x, 20), min(s.y, 20), min(s.z, 20), min(s.w, 20)};
#pragma unroll
    for (int h = 0; h < 8; ++h) {
        uchar4 o;
        float v;
        v = (eeS[ex[0]][h] + deS[sx[0]][h]) * LOG2E_ + 0.5f;
        o.x = (unsigned char)(int)fminf(fmaxf(v * 255.f + 0.5f, 0.f), 255.f);
        v = (eeS[ex[1]][h] + deS[sx[1]][h]) * LOG2E_ + 0.5f;
        o.y = (unsigned char)(int)fminf(fmaxf(v * 255.f + 0.5f, 0.f), 255.f);
        v = (eeS[ex[2]][h] + deS[sx[2]][h]) * LOG2E_ + 0.5f;
        o.z = (unsigned char)(int)fminf(fmaxf(v * 255.f + 0.5f, 0.f), 255.f);
        v = (eeS[ex[3]][h] + deS[sx[3]][h]) * LOG2E_ + 0.5f;
        o.w = (unsigned char)(int)fminf(fmaxf(v * 255.f + 0.5f, 0.f), 255.f);
        *(uchar4*)(biasT8 + ((size_t)((b * H_ + h) * T_ + i)) * T_ + j4) = o;
    }
}

// ---------------------------------------------------------------------------
// Embedding as MFMA GEMM, 128x64 tile, K=128. 4-buffer counted-vmcnt pipe.
// 1-D grid 256, XCD-swizzled decode (x8, y32).
// ---------------------------------------------------------------------------
__global__ __launch_bounds__(256) void embed_mm_k(
    const short* __restrict__ A, const short* __restrict__ Wt,
    const float* __restrict__ nb, const float* __restrict__ cb,
    const float* __restrict__ cW, const float* __restrict__ cent,
    float* __restrict__ C)
{
    const int K = F_, N = D_;
    __shared__ short As[4][128 * 32];
    __shared__ short Bs[4][64 * 32];
    const int tid  = threadIdx.x;
    const int lane = tid & 63, wv = tid >> 6;
    const int lb = blockIdx.x;
    const int xcd = lb & 7, jj = lb >> 3;            // jj in 0..31
    const int bx = jj & 7, by = (xcd << 2) + (jj >> 3);
    const int bm = by << 7, bn = bx << 6;
    const int wm = (wv & 1) << 6, wn = (wv >> 1) << 5;

    const int c0 = (wv << 6) + lane;
    const int m0 = c0 >> 2, q0 = (c0 & 3) ^ ((m0 >> 1) & 3);
    const int c1 = 256 + c0;
    const int m1 = c1 >> 2, q1 = (c1 & 3) ^ ((m1 >> 1) & 3);

    const short* gA0 = A  + (size_t)(bm + m0) * K + (q0 << 3);
    const short* gA1 = A  + (size_t)(bm + m1) * K + (q1 << 3);
    const short* gB0 = Wt + (size_t)(bn + m0) * K + (q0 << 3);

    f32x4 acc[4][2];
#pragma unroll
    for (int i = 0; i < 4; ++i)
#pragma unroll
        for (int j = 0; j < 2; ++j)
            acc[i][j] = (f32x4){0.f, 0.f, 0.f, 0.f};

    const int fm = lane & 15, fq = lane >> 4;
    int caddr[4], baddr[2];
#pragma unroll
    for (int t = 0; t < 4; ++t) {
        const int rowA = wm + (t << 4) + fm;
        caddr[t] = ((rowA << 2) + (fq ^ ((rowA >> 1) & 3))) << 3;
    }
#pragma unroll
    for (int t = 0; t < 2; ++t) {
        const int rowB = wn + (t << 4) + fm;
        baddr[t] = ((rowB << 2) + (fq ^ ((rowB >> 1) & 3))) << 3;
    }

#define EMB_STAGE(KK, BUF) do { \
    __builtin_amdgcn_global_load_lds(AS1(gA0 + (KK)), AS3(&As[BUF][(wv << 9)]),        16, 0, 0); \
    __builtin_amdgcn_global_load_lds(AS1(gA1 + (KK)), AS3(&As[BUF][2048 + (wv << 9)]), 16, 0, 0); \
    __builtin_amdgcn_global_load_lds(AS1(gB0 + (KK)), AS3(&Bs[BUF][(wv << 9)]),        16, 0, 0); \
} while (0)

    EMB_STAGE(0, 0); EMB_STAGE(32, 1); EMB_STAGE(64, 2);
    const int nt = K >> 5;                           // 4
    for (int t = 0; t < nt; ++t) {
        const int rem = nt - 1 - t;
        PIPE_BARRIER(rem, 6, 3);
        if (rem >= 3) EMB_STAGE((t + 3) << 5, (t + 3) & 3);
        const short* Asc = As[t & 3];
        const short* Bsc = Bs[t & 3];
        bf16x8 af[4], bf[2];
#pragma unroll
        for (int u = 0; u < 4; ++u) af[u] = *(const bf16x8*)(Asc + caddr[u]);
#pragma unroll
        for (int u = 0; u < 2; ++u) bf[u] = *(const bf16x8*)(Bsc + baddr[u]);
#pragma unroll
        for (int i = 0; i < 4; ++i)
#pragma unroll
            for (int j = 0; j < 2; ++j)
                acc[i][j] = __builtin_amdgcn_mfma_f32_16x16x32_bf16(
                    af[i], bf[j], acc[i][j], 0, 0, 0);
    }
#undef EMB_STAGE

    const int col0 = bn + wn + fm;
    const int row0 = bm + wm + (fq << 2);
#pragma unroll
    for (int j = 0; j < 2; ++j) {
        const int colg = col0 + (j << 4);
        const float bb = nb[colg] + cb[colg];
        const float cw = cW[colg];
#pragma unroll
        for (int i = 0; i < 4; ++i) {
#pragma unroll
            for (int r = 0; r < 4; ++r) {
                const int rowg = row0 + (i << 4) + r;
                C[(size_t)rowg * N + colg] = acc[i][j][r] + bb + cent[rowg] * cw;
            }
        }
    }
}

// ---------------------------------------------------------------------------
// bf16 MFMA GEMM, 128x128 tile: C = act(A @ Wt^T + bias) (+R)
// 4-buffer counted-vmcnt pipeline. 1-D grid, XCD decode for N=2048 (x16,y32).
// ---------------------------------------------------------------------------
template <int OUTM, int ACT, int RES>
__global__ __launch_bounds__(256) void mm_k(
    const short* __restrict__ A, const short* __restrict__ Wt,
    const float* __restrict__ bias, const float* __restrict__ R,
    void* __restrict__ Cv, int M, int N, int K)
{
    __shared__ short As[4][128 * 32];
    __shared__ short Bs[4][128 * 32];
    const int tid  = threadIdx.x;
    const int lane = tid & 63, wv = tid >> 6;
    const int lb = blockIdx.x;
    const int xcd = lb & 7, jj = lb >> 3;            // jj in 0..63
    const int bx = jj & 15, by = (xcd << 2) + (jj >> 4);
    const int bm = by << 7, bn = bx << 7;
    const int wm = (wv & 1) << 6, wn = (wv >> 1) << 6;

    const int c0 = (wv << 6) + lane;
    const int m0 = c0 >> 2, q0 = (c0 & 3) ^ ((m0 >> 1) & 3);
    const int c1 = 256 + c0;
    const int m1 = c1 >> 2, q1 = (c1 & 3) ^ ((m1 >> 1) & 3);

    const short* gA0 = A  + (size_t)(bm + m0) * K + (q0 << 3);
    const short* gA1 = A  + (size_t)(bm + m1) * K + (q1 << 3);
    const short* gB0 = Wt + (size_t)(bn + m0) * K + (q0 << 3);
    const short* gB1 = Wt + (size_t)(bn + m1) * K + (q1 << 3);

    f32x4 acc[4][4];
#pragma unroll
    for (int i = 0; i < 4; ++i)
#pragma unroll
        for (int j = 0; j < 4; ++j)
            acc[i][j] = (f32x4){0.f, 0.f, 0.f, 0.f};

    const int fm = lane & 15, fq = lane >> 4;
    int caddr[4], baddr[4];
#pragma unroll
    for (int t = 0; t < 4; ++t) {
        const int rowA = wm + (t << 4) + fm;
        caddr[t] = ((rowA << 2) + (fq ^ ((rowA >> 1) & 3))) << 3;
        const int rowB = wn + (t << 4) + fm;
        baddr[t] = ((rowB << 2) + (fq ^ ((rowB >> 1) & 3))) << 3;
    }

#define MM_STAGE(KK, BUF) do { \
    __builtin_amdgcn_global_load_lds(AS1(gA0 + (KK)), AS3(&As[BUF][(wv << 9)]),        16, 0, 0); \
    __builtin_amdgcn_global_load_lds(AS1(gA1 + (KK)), AS3(&As[BUF][2048 + (wv << 9)]), 16, 0, 0); \
    __builtin_amdgcn_global_load_lds(AS1(gB0 + (KK)), AS3(&Bs[BUF][(wv << 9)]),        16, 0, 0); \
    __builtin_amdgcn_global_load_lds(AS1(gB1 + (KK)), AS3(&Bs[BUF][2048 + (wv << 9)]), 16, 0, 0); \
} while (0)

    MM_STAGE(0, 0); MM_STAGE(32, 1); MM_STAGE(64, 2);
    const int nt = K >> 5;
    for (int t = 0; t < nt; ++t) {
        const int rem = nt - 1 - t;
        PIPE_BARRIER(rem, 8, 4);
        if (rem >= 3) MM_STAGE((t + 3) << 5, (t + 3) & 3);
        const short* Asc = As[t & 3];
        const short* Bsc = Bs[t & 3];
        bf16x8 af[4], bf[4];
#pragma unroll
        for (int u = 0; u < 4; ++u) {
            af[u] = *(const bf16x8*)(Asc + caddr[u]);
            bf[u] = *(const bf16x8*)(Bsc + baddr[u]);
        }
#pragma unroll
        for (int i = 0; i < 4; ++i)
#pragma unroll
            for (int j = 0; j < 4; ++j)
                acc[i][j] = __builtin_amdgcn_mfma_f32_16x16x32_bf16(
                    af[i], bf[j], acc[i][j], 0, 0, 0);
    }
#undef MM_STAGE

    const int col0 = bn + wn + fm;
    const int row0 = bm + wm + (fq << 2);
    float* Cf = (float*)Cv;
    short* Cb = (short*)Cv;
#pragma unroll
    for (int j = 0; j < 4; ++j) {
        const int colg = col0 + (j << 4);
        const float bb = bias[colg];
#pragma unroll
        for (int i = 0; i < 4; ++i) {
#pragma unroll
            for (int r = 0; r < 4; ++r) {
                const int rowg = row0 + (i << 4) + r;
                float v = acc[i][j][r] + bb;
                if (ACT) v = v / (1.f + __expf(-v));
                const size_t off = (size_t)rowg * N + colg;
                if (RES) v += R[off];
                if (OUTM == 1) Cb[off] = f2bf(v);
                else           Cf[off] = v;
            }
        }
    }
}

// ---------------------------------------------------------------------------
// QKV GEMM, 128x64 tile. N=1536 fixed. 4-buffer counted-vmcnt pipeline.
// 1-D grid 768, XCD decode (x24, y32).
// ---------------------------------------------------------------------------
__global__ __launch_bounds__(256) void qkv64_k(
    const short* __restrict__ A, const short* __restrict__ Wt,
    const float* __restrict__ bias, short* __restrict__ QKb,
    short* __restrict__ VtOut)
{
    const int K = D_;
    __shared__ short As[4][128 * 32];
    __shared__ short Bs[4][64 * 32];
    const int tid  = threadIdx.x;
    const int lane = tid & 63, wv = tid >> 6;
    const int lb = blockIdx.x;
    const int xcd = lb & 7, jj = lb >> 3;            // jj in 0..95
    const int yl = jj / 24, bx = jj - yl * 24;
    const int by = (xcd << 2) + yl;
    const int bm = by << 7, bn = bx << 6;
    const int wm = (wv & 1) << 6, wn = (wv >> 1) << 5;

    const int c0 = (wv << 6) + lane;
    const int m0 = c0 >> 2, q0 = (c0 & 3) ^ ((m0 >> 1) & 3);
    const int c1 = 256 + c0;
    const int m1 = c1 >> 2, q1 = (c1 & 3) ^ ((m1 >> 1) & 3);

    const short* gA0 = A  + (size_t)(bm + m0) * K + (q0 << 3);
    const short* gA1 = A  + (size_t)(bm + m1) * K + (q1 << 3);
    const short* gB0 = Wt + (size_t)(bn + m0) * K + (q0 << 3);

    f32x4 acc[4][2];
#pragma unroll
    for (int i = 0; i < 4; ++i)
#pragma unroll
        for (int j = 0; j < 2; ++j)
            acc[i][j] = (f32x4){0.f, 0.f, 0.f, 0.f};

    const int fm = lane & 15, fq = lane >> 4;
    int caddr[4], baddr[2];
#pragma unroll
    for (int t = 0; t < 4; ++t) {
        const int rowA = wm + (t << 4) + fm;
        caddr[t] = ((rowA << 2) + (fq ^ ((rowA >> 1) & 3))) << 3;
    }
#pragma unroll
    for (int t = 0; t < 2; ++t) {
        const int rowB = wn + (t << 4) + fm;
        baddr[t] = ((rowB << 2) + (fq ^ ((rowB >> 1) & 3))) << 3;
    }

#define QKV_STAGE(KK, BUF) do { \
    __builtin_amdgcn_global_load_lds(AS1(gA0 + (KK)), AS3(&As[BUF][(wv << 9)]),        16, 0, 0); \
    __builtin_amdgcn_global_load_lds(AS1(gA1 + (KK)), AS3(&As[BUF][2048 + (wv << 9)]), 16, 0, 0); \
    __builtin_amdgcn_global_load_lds(AS1(gB0 + (KK)), AS3(&Bs[BUF][(wv << 9)]),        16, 0, 0); \
} while (0)

    QKV_STAGE(0, 0); QKV_STAGE(32, 1); QKV_STAGE(64, 2);
    const int nt = K >> 5;
    for (int t = 0; t < nt; ++t) {
        const int rem = nt - 1 - t;
        PIPE_BARRIER(rem, 6, 3);
        if (rem >= 3) QKV_STAGE((t + 3) << 5, (t + 3) & 3);
        const short* Asc = As[t & 3];
        const short* Bsc = Bs[t & 3];
        bf16x8 af[4], bf[2];
#pragma unroll
        for (int u = 0; u < 4; ++u) af[u] = *(const bf16x8*)(Asc + caddr[u]);
#pragma unroll
        for (int u = 0; u < 2; ++u) bf[u] = *(const bf16x8*)(Bsc + baddr[u]);
#pragma unroll
        for (int i = 0; i < 4; ++i)
#pragma unroll
            for (int j = 0; j < 2; ++j)
                acc[i][j] = __builtin_amdgcn_mfma_f32_16x16x32_bf16(
                    af[i], bf[j], acc[i][j], 0, 0, 0);
    }
#undef QKV_STAGE

    const int col0 = bn + wn + fm;
    const int row0 = bm + wm + (fq << 2);
#pragma unroll
    for (int j = 0; j < 2; ++j) {
        const int colg = col0 + (j << 4);
        const float bb = bias[colg];
#pragma unroll
        for (int i = 0; i < 4; ++i) {
#pragma unroll
            for (int r = 0; r < 4; ++r) {
                const int rowg = row0 + (i << 4) + r;
                const float v = acc[i][j][r] + bb;
                if (colg < 1024) {
                    QKb[(size_t)rowg * 1024 + colg] = f2bf(v);
                } else {
                    const int da = colg - 1024;
                    const int hh = da >> 6, dd = da & 63;
                    const int bb2 = rowg >> 10, tt = rowg & 1023;
                    VtOut[((size_t)(bb2 * H_ + hh) * 64 + dd) * T_ + tt] = f2bf(v);
                }
            }
        }
    }
}

// ---------------------------------------------------------------------------
// MFMA flash attention v3.2 (single-buffered; 29 KB LDS, 4 blocks/CU).
// grid (2*T/64, H, B), 256 threads = 4 waves.
// ---------------------------------------------------------------------------
__global__ __launch_bounds__(256) void flash_k(
    const short* __restrict__ QKb, const short* __restrict__ Vt,
    const unsigned char* __restrict__ biasT8, short* __restrict__ OpartB,
    float* __restrict__ Lpart)
{
    const int tid = threadIdx.x;
    const int bx = blockIdx.x;
    const int it = bx >> 1, split = bx & 1;
    const int i0 = it << 6;
    const int h  = blockIdx.y;
    const int b  = blockIdx.z;
    const int lane = tid & 63, w = tid >> 6;
    const int fm = lane & 15, q = lane >> 4;

    __shared__ short Ks[4096];
    __shared__ short Vs[4096];
    __shared__ unsigned char Bsh8[4096];
    __shared__ short Ps[64][72];

    const short* qp = QKb + (size_t)(b * T_ + i0 + (w << 4) + fm) * 1024 + (h << 6) + (q << 3);
    const bf16x8 aq0 = *(const bf16x8*)(qp);
    const bf16x8 aq1 = *(const bf16x8*)(qp + 32);

    const int s0 = (w << 6) + lane, r0 = s0 >> 3, cc0 = (s0 & 7) ^ (r0 & 7);
    const int s1 = 256 + s0,        r1 = s1 >> 3, cc1 = (s1 & 7) ^ (r1 & 7);
    const short* gK0 = QKb + (size_t)(b * T_ + r0) * 1024 + 512 + (h << 6) + (cc0 << 3);
    const short* gK1 = QKb + (size_t)(b * T_ + r1) * 1024 + 512 + (h << 6) + (cc1 << 3);
    const short* gV0 = Vt + ((size_t)((b * H_ + h) << 6) + r0) * T_ + (cc0 << 3);
    const short* gV1 = Vt + ((size_t)((b * H_ + h) << 6) + r1) * T_ + (cc1 << 3);
    const int br = s0 >> 2, bc = (s0 & 3) ^ (br & 3);
    const unsigned char* gB0 = biasT8 +
        ((size_t)(b * H_ + h) * T_ + i0 + br) * T_ + (bc << 4);

    int fAddr[4][2];
#pragma unroll
    for (int t = 0; t < 4; ++t) {
        const int row = (t << 4) + fm;
#pragma unroll
        for (int ks = 0; ks < 2; ++ks)
            fAddr[t][ks] = (row << 6) + (((q + (ks << 2)) ^ (row & 7)) << 3);
    }

    int bAddr[4][4];
#pragma unroll
    for (int r = 0; r < 4; ++r) {
        const int rowL = (w << 4) + (q << 2) + r;
#pragma unroll
        for (int jt = 0; jt < 4; ++jt)
            bAddr[r][jt] = (rowL << 6) + (((jt ^ (rowL & 3))) << 4) + fm;
    }

    const short oneb = 0x3F80;                   // bf16 1.0
    const bf16x8 ones = {oneb, oneb, oneb, oneb, oneb, oneb, oneb, oneb};

    f32x4 accO[4];
#pragma unroll
    for (int dt = 0; dt < 4; ++dt) accO[dt] = (f32x4){0.f, 0.f, 0.f, 0.f};
    f32x4 accL = (f32x4){0.f, 0.f, 0.f, 0.f};

    const int irow = b * T_ + i0 + (w << 4) + (q << 2);
    short* psW = &Ps[(w << 4) + (q << 2)][fm];
    const short* psR = &Ps[(w << 4) + fm][q << 3];

    const int jbeg = split << 9, jend = jbeg + 512;
    for (int j0 = jbeg; j0 < jend; j0 += 64) {
        __syncthreads();
        __builtin_amdgcn_global_load_lds(AS1(gK0 + (size_t)j0 * 1024), AS3(Ks + (s0 << 3)), 16, 0, 0);
        __builtin_amdgcn_global_load_lds(AS1(gK1 + (size_t)j0 * 1024), AS3(Ks + (s1 << 3)), 16, 0, 0);
        __builtin_amdgcn_global_load_lds(AS1(gV0 + j0), AS3(Vs + (s0 << 3)), 16, 0, 0);
        __builtin_amdgcn_global_load_lds(AS1(gV1 + j0), AS3(Vs + (s1 << 3)), 16, 0, 0);
        __builtin_amdgcn_global_load_lds(AS1(gB0 + j0), AS3(Bsh8 + (s0 << 4)), 16, 0, 0);
        __syncthreads();

        f32x4 s[4];
#pragma unroll
        for (int jt = 0; jt < 4; ++jt) s[jt] = (f32x4){0.f, 0.f, 0.f, 0.f};
#pragma unroll
        for (int jt = 0; jt < 4; ++jt) {
            const bf16x8 k0 = *(const bf16x8*)(Ks + fAddr[jt][0]);
            const bf16x8 k1 = *(const bf16x8*)(Ks + fAddr[jt][1]);
            s[jt] = __builtin_amdgcn_mfma_f32_16x16x32_bf16(aq0, k0, s[jt], 0, 0, 0);
            s[jt] = __builtin_amdgcn_mfma_f32_16x16x32_bf16(aq1, k1, s[jt], 0, 0, 0);
        }

#pragma unroll
        for (int r = 0; r < 4; ++r)
#pragma unroll
            for (int jt = 0; jt < 4; ++jt) {
                const float q8 = (float)Bsh8[bAddr[r][jt]];
                const float bb = fmaf(q8, 1.f / 255.f, -0.5f);
                const float p = __builtin_amdgcn_exp2f(fmaf(s[jt][r], CL2E_, bb));
                psW[(size_t)r * 72 + (jt << 4)] = f2bf(p);
            }

#pragma unroll
        for (int ks = 0; ks < 2; ++ks) {
            const bf16x8 ap = *(const bf16x8*)(psR + (ks << 5));
            accL = __builtin_amdgcn_mfma_f32_16x16x32_bf16(ap, ones, accL, 0, 0, 0);
#pragma unroll
            for (int dt = 0; dt < 4; ++dt) {
                const bf16x8 bv = *(const bf16x8*)(Vs + fAddr[dt][ks]);
                accO[dt] = __builtin_amdgcn_mfma_f32_16x16x32_bf16(ap, bv, accO[dt], 0, 0, 0);
            }
        }
    }

    short* obase = OpartB + (size_t)split * B_ * T_ * D_;
#pragma unroll
    for (int r = 0; r < 4; ++r) {
        short* op = obase + (size_t)(irow + r) * D_ + (h << 6) + fm;
#pragma unroll
        for (int dt = 0; dt < 4; ++dt)
            op[dt << 4] = f2bf(accO[dt][r]);
    }
    if (fm == 0) {
#pragma unroll
        for (int r = 0; r < 4; ++r)
            Lpart[(size_t)split * B_ * T_ * H_ + (size_t)(irow + r) * H_ + h] = accL[r];
    }
}

// ---------------------------------------------------------------------------
// Combine split-K attention partials: Ob = bf16((O0+O1) / (l0+l1))
// ---------------------------------------------------------------------------
__global__ __launch_bounds__(256) void combine_k(
    const short* __restrict__ OpartB, const float* __restrict__ Lpart,
    short* __restrict__ Ob)
{
    const int gid = blockIdx.x * 256 + threadIdx.x;   // over M*D/4
    const int d4  = (gid & 127) << 2;
    const int row = gid >> 7;
    const int h   = d4 >> 6;
    const float l = Lpart[(size_t)row * H_ + h] +
                    Lpart[(size_t)B_ * T_ * H_ + (size_t)row * H_ + h];
    const float inv = 1.f / l;
    const size_t o = (size_t)row * D_ + d4;
    const short4 a = *(const short4*)(OpartB + o);
    const short4 c = *(const short4*)(OpartB + (size_t)B_ * T_ * D_ + o);
    short4 r = make_short4(
        f2bf((bf2f(a.x) + bf2f(c.x)) * inv), f2bf((bf2f(a.y) + bf2f(c.y)) * inv),
        f2bf((bf2f(a.z) + bf2f(c.z)) * inv), f2bf((bf2f(a.w) + bf2f(c.w)) * inv));
    *(short4*)(Ob + o) = r;
}

// ---------------------------------------------------------------------------
// bf16 MFMA GEMM, 128x64 tile, N=512, SPLIT-K x2 via fp32 PARTIAL BUFFERS
// (no atomics). P[z] = A[:, z*KS:(z+1)*KS] @ Wt^T + (z==0 ? bias : 0).
// Reduction (H += P0 + P1) is folded into the next ln_k / red_k.
// 4-buffer counted-vmcnt pipeline; 1-D grid 512 = 2 blocks/CU (TLP x2 on
// top of the ILP pipeline — round-3 had the pipeline at 1 block/CU, round-2
// had TLP without a working pipeline; this combines them).
// XCD decode: per XCD, 4 M-panels x both K-halves x all 8 N-tiles.
// ---------------------------------------------------------------------------
__global__ __launch_bounds__(256) void mm64p_k(
    const short* __restrict__ A, const short* __restrict__ Wt,
    const float* __restrict__ bias, float* __restrict__ P,
    int M, int N, int K, int KS)
{
    __shared__ short As[4][128 * 32];
    __shared__ short Bs[4][64 * 32];
    const int tid  = threadIdx.x;
    const int lane = tid & 63, wv = tid >> 6;
    const int lb = blockIdx.x;
    const int xcd = lb & 7, jj = lb >> 3;            // jj in 0..63
    const int z  = jj >> 5;                          // K-half
    const int jr = jj & 31;
    const int bx = jr & 7, by = (xcd << 2) + (jr >> 3);
    const int bm = by << 7, bn = bx << 6;
    const int ks0 = z * KS;
    const int wm = (wv & 1) << 6, wn = (wv >> 1) << 5;

    const int c0 = (wv << 6) + lane;
    const int m0 = c0 >> 2, q0 = (c0 & 3) ^ ((m0 >> 1) & 3);
    const int c1 = 256 + c0;
    const int m1 = c1 >> 2, q1 = (c1 & 3) ^ ((m1 >> 1) & 3);

    const short* gA0 = A  + (size_t)(bm + m0) * K + ks0 + (q0 << 3);
    const short* gA1 = A  + (size_t)(bm + m1) * K + ks0 + (q1 << 3);
    const short* gB0 = Wt + (size_t)(bn + m0) * K + ks0 + (q0 << 3);

    f32x4 acc[4][2];
#pragma unroll
    for (int i = 0; i < 4; ++i)
#pragma unroll
        for (int j = 0; j < 2; ++j)
            acc[i][j] = (f32x4){0.f, 0.f, 0.f, 0.f};

    const int fm = lane & 15, fq = lane >> 4;
    int caddr[4], baddr[2];
#pragma unroll
    for (int t = 0; t < 4; ++t) {
        const int rowA = wm + (t << 4) + fm;
        caddr[t] = ((rowA << 2) + (fq ^ ((rowA >> 1) & 3))) << 3;
    }
#pragma unroll
    for (int t = 0; t < 2; ++t) {
        const int rowB = wn + (t << 4) + fm;
        baddr[t] = ((rowB << 2) + (fq ^ ((rowB >> 1) & 3))) << 3;
    }

#define MM64_STAGE(KK, BUF) do { \
    __builtin_amdgcn_global_load_lds(AS1(gA0 + (KK)), AS3(&As[BUF][(wv << 9)]),        16, 0, 0); \
    __builtin_amdgcn_global_load_lds(AS1(gA1 + (KK)), AS3(&As[BUF][2048 + (wv << 9)]), 16, 0, 0); \
    __builtin_amdgcn_global_load_lds(AS1(gB0 + (KK)), AS3(&Bs[BUF][(wv << 9)]),        16, 0, 0); \
} while (0)

    MM64_STAGE(0, 0); MM64_STAGE(32, 1); MM64_STAGE(64, 2);
    const int nt = KS >> 5;
    for (int t = 0; t < nt; ++t) {
        const int rem = nt - 1 - t;
        PIPE_BARRIER(rem, 6, 3);
        if (rem >= 3) MM64_STAGE((t + 3) << 5, (t + 3) & 3);
        const short* Asc = As[t & 3];
        const short* Bsc = Bs[t & 3];
        bf16x8 af[4], bf[2];
#pragma unroll
        for (int u = 0; u < 4; ++u) af[u] = *(const bf16x8*)(Asc + caddr[u]);
#pragma unroll
        for (int u = 0; u < 2; ++u) bf[u] = *(const bf16x8*)(Bsc + baddr[u]);
#pragma unroll
        for (int i = 0; i < 4; ++i)
#pragma unroll
            for (int j = 0; j < 2; ++j)
                acc[i][j] = __builtin_amdgcn_mfma_f32_16x16x32_bf16(
                    af[i], bf[j], acc[i][j], 0, 0, 0);
    }
#undef MM64_STAGE

    const int col0 = bn + wn + fm;
    const int row0 = bm + wm + (fq << 2);
    float* Pz = P + (size_t)z * M * N;
#pragma unroll
    for (int j = 0; j < 2; ++j) {
        const int colg = col0 + (j << 4);
        const float bb = (z == 0) ? bias[colg] : 0.f;
#pragma unroll
        for (int i = 0; i < 4; ++i) {
#pragma unroll
            for (int r = 0; r < 4; ++r) {
                const int rowg = row0 + (i << 4) + r;
                Pz[(size_t)rowg * N + colg] = acc[i][j][r] + bb;
            }
        }
    }
}

// ---------------------------------------------------------------------------
extern "C" void kernel_launch(void* const* d_in, const int* in_sizes, int n_in,
                              void* d_out, int out_size, void* d_ws, size_t ws_size,
                              hipStream_t stream)
{
    (void)in_sizes; (void)n_in; (void)out_size; (void)ws_size;

    const float* nf   = (const float*)d_in[0];
    const float* cent = (const float*)d_in[1];
    const int*   et   = (const int*)  d_in[2];
    const int*   sp   = (const int*)  d_in[3];
    const float* nW   = (const float*)d_in[4];
    const float* nb   = (const float*)d_in[5];
    const float* cW   = (const float*)d_in[6];
    const float* cb   = (const float*)d_in[7];
    const float* ee   = (const float*)d_in[8];
    const float* de   = (const float*)d_in[9];
    const float* ln1w = (const float*)d_in[10];
    const float* ln1b = (const float*)d_in[11];
    const float* qW   = (const float*)d_in[12];
    const float* qb   = (const float*)d_in[13];
    const float* kW   = (const float*)d_in[14];
    const float* kb   = (const float*)d_in[15];
    const float* vW   = (const float*)d_in[16];
    const float* vb   = (const float*)d_in[17];
    const float* oW   = (const float*)d_in[18];
    const float* ob   = (const float*)d_in[19];
    const float* ln2w = (const float*)d_in[20];
    const float* ln2b = (const float*)d_in[21];
    const float* f1W  = (const float*)d_in[22];
    const float* f1b  = (const float*)d_in[23];
    const float* f2W  = (const float*)d_in[24];
    const float* f2b  = (const float*)d_in[25];

    const int M = B_ * T_;                          // 4096
    char* p = (char*)d_ws;
    float* Hbuf  = (float*)p;  p += (size_t)M * D_ * 4;                    // 8 MB
    short* QKb   = (short*)p;  p += (size_t)M * 1024 * 2;                  // 8 MB
    short* Vt    = (short*)p;  p += (size_t)B_ * H_ * 64 * T_ * 2;         // 4 MB
    float* biasf = (float*)p;  p += (size_t)L_ * 3 * D_ * 4;               // 24 KB
    short* Xbuf  = (short*)p;  p += (size_t)M * D_ * 2;                    // 4 MB
    short* Ob    = (short*)p;  p += (size_t)M * D_ * 2;                    // 4 MB
    short* FF    = (short*)p;  p += (size_t)M * DFF_ * 2;                  // 16 MB
    unsigned char* biasT8 = (unsigned char*)p; p += (size_t)B_ * H_ * T_ * T_; // 33.5 MB
    short* WqkvT = (short*)p;  p += (size_t)L_ * 3 * D_ * D_ * 2;
    short* WoT   = (short*)p;  p += (size_t)L_ * D_ * D_ * 2;
    short* Wf1T  = (short*)p;  p += (size_t)L_ * DFF_ * D_ * 2;
    short* Wf2T  = (short*)p;  p += (size_t)L_ * D_ * DFF_ * 2;
    short* nfb   = (short*)p;  p += (size_t)M * F_ * 2;                    // 1 MB
    short* nWt   = (short*)p;  p += (size_t)D_ * F_ * 2;                   // 128 KB
    short* OpartB = (short*)p; p += (size_t)2 * M * D_ * 2;                // 8 MB
    float* Lpart = (float*)p;  p += (size_t)2 * M * H_ * 4;                // 256 KB
    float* Pbuf  = (float*)p;  p += (size_t)2 * M * D_ * 4;                // 16 MB

    float* out = (float*)d_out;

    // ---- prep (3 dispatches)
    transpose_all_k<<<dim3(1024, 25), dim3(32, 8), 0, stream>>>(
        qW, kW, vW, oW, f1W, f2W, nW, WqkvT, WoT, Wf1T, Wf2T, nWt);
    prep_k<<<dim3(4632), dim3(256), 0, stream>>>(
        et, sp, ee, de, biasT8, nf, nfb, qb, kb, vb, biasf);
    embed_mm_k<<<dim3(256), dim3(256), 0, stream>>>(
        nfb, nWt, nb, cb, cW, cent, Hbuf);

    const dim3 blk(256);
    const dim3 gQKV(768);                     // 1-D, XCD decode inside
    const dim3 gO64p(512);                    // split-K x2, 2 blocks/CU
    const dim3 gF1 (512);
    const dim3 gAttn(2 * T_ / 64, H_, B_);    // (32, 8, 4) = 1024 blocks
    const dim3 gCmb(M * D_ / 1024);           // 2048 blocks

    for (int l = 0; l < L_; ++l) {
        const size_t bOff  = (size_t)l * D_;
        const size_t b1Off = (size_t)l * DFF_;

        // ln1: layer 0 reads Hbuf directly; later layers fold the previous
        // FF2 split-K reduction (Hbuf += P0 + P1) first.
        if (l == 0)
            ln_k<0><<<dim3(M), blk, 0, stream>>>(
                Hbuf, nullptr, nullptr, ln1w + bOff, ln1b + bOff, Xbuf);
        else
            ln_k<2><<<dim3(M), blk, 0, stream>>>(
                Hbuf, Pbuf, Pbuf + (size_t)M * D_, ln1w + bOff, ln1b + bOff, Xbuf);

        qkv64_k<<<gQKV, blk, 0, stream>>>(
            Xbuf, WqkvT + (size_t)l * 3 * D_ * D_, biasf + (size_t)l * 3 * D_,
            QKb, Vt);

        flash_k<<<gAttn, blk, 0, stream>>>(QKb, Vt, biasT8, OpartB, Lpart);
        combine_k<<<gCmb, blk, 0, stream>>>(OpartB, Lpart, Ob);

        // O-proj: P0,P1 = Ob @ WoT (split-K x2); reduced in ln2 below.
        mm64p_k<<<gO64p, blk, 0, stream>>>(
            Ob, WoT + (size_t)l * D_ * D_, ob + bOff, Pbuf, M, D_, D_, D_ / 2);

        // ln2 folds Hbuf += P0 + P1, then LayerNorms.
        ln_k<2><<<dim3(M), blk, 0, stream>>>(
            Hbuf, Pbuf, Pbuf + (size_t)M * D_, ln2w + bOff, ln2b + bOff, Xbuf);

        mm_k<1, 1, 0><<<gF1, blk, 0, stream>>>(
            Xbuf, Wf1T + (size_t)l * DFF_ * D_, f1b + b1Off, nullptr, FF, M, DFF_, D_);

        // FF2: P0,P1 = FF @ Wf2T (split-K x2); reduced by next ln1 / red_k.
        mm64p_k<<<gO64p, blk, 0, stream>>>(
            FF, Wf2T + (size_t)l * D_ * DFF_, f2b + bOff, Pbuf, M, D_, DFF_, DFF_ / 2);
    }

    // Final: out = Hbuf + P0 + P1 (last FF2's reduction)
    red_k<<<gCmb, blk, 0, stream>>>(Hbuf, Pbuf, Pbuf + (size_t)M * D_, out);
}